// Round 8
// baseline (2308.957 us; speedup 1.0000x reference)
//
#include <hip/hip_runtime.h>

#define B_ 64
#define R_ 196
#define F_ 2048
#define E_ 512
#define H_ 512
#define A_ 512
#define V_ 12000
#define L_ 24

typedef __attribute__((ext_vector_type(8))) short bf16x8;
typedef __attribute__((ext_vector_type(4))) float f32x4;
typedef unsigned short ush;

__device__ __forceinline__ float fast_tanh(float x) {
    float t = __expf(2.f * x);
    return 1.f - 2.f / (t + 1.f);
}
__device__ __forceinline__ float fast_sig(float x) {
    return 1.f / (1.f + __expf(-x));
}
__device__ __forceinline__ ush f2bf(float x) {
    unsigned int u = __float_as_uint(x);
    return (ush)((u + 0x7fffu + ((u >> 16) & 1u)) >> 16);
}
__device__ __forceinline__ float bf2f(ush b) {
    return __uint_as_float(((unsigned int)b) << 16);
}

#define LROW 40   // LDS row stride (32 k-elems + 8 pad)

// ---------------------------------------------------------------------------
// gemm_big128: C = A @ W^T (+bias). Tile 128M x 256N, BK=32, 512 threads
// (8 waves: 2 m-waves x 4 n-waves). Used for the pred GEMM (564 blocks).
// Bijective XCD-chunked swizzle. SPLIT=3: (hi,lo) bf16x2, 3 MFMAs.
// CMAP=2: pred layout C[(m&63)*L*V + (m>>6)*V + n] fp32 NT stores.
// ---------------------------------------------------------------------------
template<int SPLIT, int CMAP, bool NFAST>
__global__ __launch_bounds__(512) void gemm_big128(
    const ush* __restrict__ Ah, const ush* __restrict__ Al, int lda,
    const ush* __restrict__ Wh, const ush* __restrict__ Wl, int ldw,
    const float* __restrict__ bias, void* __restrict__ Cv,
    int ldc, int N, int K)
{
    constexpr int SMEM_BYTES = (SPLIT == 3) ? 61440 : 30720;
    __shared__ __align__(16) char smem[SMEM_BYTES];
    ush* sAh = (ush*)smem;                    // 128 x LROW = 10240 B
    ush* sBh = (ush*)(smem + 10240);          // 256 x LROW = 20480 B
    ush* sAl = (ush*)(smem + 30720);
    ush* sBl = (ush*)(smem + 40960);

    const int tid = threadIdx.x;
    const int lane = tid & 63, w = tid >> 6;
    const int mw = w >> 2, nw = w & 3;

    const int nbx = gridDim.x, nby = gridDim.y;
    const int nwg = nbx * nby;
    const int orig = blockIdx.x + nbx * blockIdx.y;
    const int q = nwg >> 3, r = nwg & 7;
    const int xcd = orig & 7, idx = orig >> 3;
    const int lin = (xcd < r ? xcd * (q + 1) : r * (q + 1) + (xcd - r) * q) + idx;
    int bx, by;
    if constexpr (NFAST) { by = lin % nby; bx = lin / nby; }
    else                 { bx = lin % nbx; by = lin / nbx; }
    const int mtile = bx * 128;
    const int ntile = by * 256;

    const int fr = lane & 15, kg = (lane >> 4) * 8;
    const int arow = tid >> 2, aq = (tid & 3) * 8;

    f32x4 acc[4][4];
    #pragma unroll
    for (int mf = 0; mf < 4; ++mf)
        #pragma unroll
        for (int nf = 0; nf < 4; ++nf) acc[mf][nf] = {0.f, 0.f, 0.f, 0.f};

    const uint4 zv = make_uint4(0u, 0u, 0u, 0u);

    for (int kb = 0; kb < K; kb += 32) {
        uint4 a_h = *(const uint4*)(Ah + (size_t)(mtile + arow) * lda + kb + aq);
        uint4 a_l;
        uint4 b_h[2], b_l[2];
        #pragma unroll
        for (int p = 0; p < 2; ++p) {
            const int row = ntile + arow + 128 * p;
            b_h[p] = (row < N) ? *(const uint4*)(Wh + (size_t)row * ldw + kb + aq) : zv;
        }
        if constexpr (SPLIT == 3) {
            a_l = *(const uint4*)(Al + (size_t)(mtile + arow) * lda + kb + aq);
            #pragma unroll
            for (int p = 0; p < 2; ++p) {
                const int row = ntile + arow + 128 * p;
                b_l[p] = (row < N) ? *(const uint4*)(Wl + (size_t)row * ldw + kb + aq) : zv;
            }
        }

        __syncthreads();
        *(uint4*)(sAh + arow * LROW + aq) = a_h;
        #pragma unroll
        for (int p = 0; p < 2; ++p)
            *(uint4*)(sBh + (arow + 128 * p) * LROW + aq) = b_h[p];
        if constexpr (SPLIT == 3) {
            *(uint4*)(sAl + arow * LROW + aq) = a_l;
            #pragma unroll
            for (int p = 0; p < 2; ++p)
                *(uint4*)(sBl + (arow + 128 * p) * LROW + aq) = b_l[p];
        }
        __syncthreads();

        bf16x8 bh[4], bl[4];
        #pragma unroll
        for (int nf = 0; nf < 4; ++nf) {
            bh[nf] = *(const bf16x8*)(sBh + (nw * 64 + nf * 16 + fr) * LROW + kg);
            if constexpr (SPLIT == 3)
                bl[nf] = *(const bf16x8*)(sBl + (nw * 64 + nf * 16 + fr) * LROW + kg);
        }
        #pragma unroll
        for (int mf = 0; mf < 4; ++mf) {
            const bf16x8 ah = *(const bf16x8*)(sAh + (mw * 64 + mf * 16 + fr) * LROW + kg);
            if constexpr (SPLIT == 3) {
                const bf16x8 al = *(const bf16x8*)(sAl + (mw * 64 + mf * 16 + fr) * LROW + kg);
                #pragma unroll
                for (int nf = 0; nf < 4; ++nf) {
                    acc[mf][nf] = __builtin_amdgcn_mfma_f32_16x16x32_bf16(ah, bh[nf], acc[mf][nf], 0, 0, 0);
                    acc[mf][nf] = __builtin_amdgcn_mfma_f32_16x16x32_bf16(ah, bl[nf], acc[mf][nf], 0, 0, 0);
                    acc[mf][nf] = __builtin_amdgcn_mfma_f32_16x16x32_bf16(al, bh[nf], acc[mf][nf], 0, 0, 0);
                }
            } else {
                #pragma unroll
                for (int nf = 0; nf < 4; ++nf)
                    acc[mf][nf] = __builtin_amdgcn_mfma_f32_16x16x32_bf16(ah, bh[nf], acc[mf][nf], 0, 0, 0);
            }
        }
    }

    #pragma unroll
    for (int nf = 0; nf < 4; ++nf) {
        const int nn = ntile + nw * 64 + nf * 16 + fr;
        if (nn < N) {
            const float bv = bias ? bias[nn] : 0.f;
            #pragma unroll
            for (int mf = 0; mf < 4; ++mf) {
                #pragma unroll
                for (int rr = 0; rr < 4; ++rr) {
                    const int m = mtile + mw * 64 + mf * 16 + (lane >> 4) * 4 + rr;
                    const float v = acc[mf][nf][rr] + bv;
                    if constexpr (CMAP == 1)
                        ((ush*)Cv)[(size_t)m * ldc + nn] = f2bf(v);
                    else if constexpr (CMAP == 2) {
                        float* dst = (float*)Cv + (size_t)(m & 63) * (L_ * V_)
                                   + (size_t)(m >> 6) * V_ + nn;
                        __builtin_nontemporal_store(v, dst);
                    } else
                        ((float*)Cv)[(size_t)m * ldc + nn] = v;
                }
            }
        }
    }
}

// ---------------------------------------------------------------------------
// gemm_big: 64M x 256N tile, 256 threads — feat_proj (392 blocks) + egates.
// ---------------------------------------------------------------------------
template<int SPLIT, int CMAP, bool NFAST>
__global__ __launch_bounds__(256) void gemm_big(
    const ush* __restrict__ Ah, const ush* __restrict__ Al, int lda,
    const ush* __restrict__ Wh, const ush* __restrict__ Wl, int ldw,
    const float* __restrict__ bias, void* __restrict__ Cv,
    int ldc, int N, int K)
{
    constexpr int SMEM_BYTES = (SPLIT == 3) ? 51200 : 25600;
    __shared__ __align__(16) char smem[SMEM_BYTES];
    ush* sAh = (ush*)smem;
    ush* sBh = (ush*)(smem + 5120);
    ush* sAl = (ush*)(smem + 25600);
    ush* sBl = (ush*)(smem + 30720);

    const int tid = threadIdx.x;
    const int lane = tid & 63, w = tid >> 6;

    const int nbx = gridDim.x, nby = gridDim.y;
    const int nwg = nbx * nby;
    int lin = blockIdx.x + nbx * blockIdx.y;
    if ((nwg & 7) == 0) {
        const int q = nwg >> 3;
        lin = (lin & 7) * q + (lin >> 3);
    }
    int bx, by;
    if constexpr (NFAST) { by = lin % nby; bx = lin / nby; }
    else                 { bx = lin % nbx; by = lin / nbx; }
    const int mtile = bx * 64;
    const int ntile = by * 256;

    const int fr = lane & 15, kg = (lane >> 4) * 8;
    const int arow = tid >> 2, aq = (tid & 3) * 8;

    f32x4 acc[4][4];
    #pragma unroll
    for (int mf = 0; mf < 4; ++mf)
        #pragma unroll
        for (int nf = 0; nf < 4; ++nf) acc[mf][nf] = {0.f, 0.f, 0.f, 0.f};

    const uint4 zv = make_uint4(0u, 0u, 0u, 0u);

    for (int kb = 0; kb < K; kb += 32) {
        uint4 a_h = *(const uint4*)(Ah + (size_t)(mtile + arow) * lda + kb + aq);
        uint4 a_l;
        uint4 b_h[4], b_l[4];
        #pragma unroll
        for (int p = 0; p < 4; ++p) {
            const int row = ntile + arow + 64 * p;
            b_h[p] = (row < N) ? *(const uint4*)(Wh + (size_t)row * ldw + kb + aq) : zv;
        }
        if constexpr (SPLIT == 3) {
            a_l = *(const uint4*)(Al + (size_t)(mtile + arow) * lda + kb + aq);
            #pragma unroll
            for (int p = 0; p < 4; ++p) {
                const int row = ntile + arow + 64 * p;
                b_l[p] = (row < N) ? *(const uint4*)(Wl + (size_t)row * ldw + kb + aq) : zv;
            }
        }

        __syncthreads();
        *(uint4*)(sAh + arow * LROW + aq) = a_h;
        #pragma unroll
        for (int p = 0; p < 4; ++p)
            *(uint4*)(sBh + (arow + 64 * p) * LROW + aq) = b_h[p];
        if constexpr (SPLIT == 3) {
            *(uint4*)(sAl + arow * LROW + aq) = a_l;
            #pragma unroll
            for (int p = 0; p < 4; ++p)
                *(uint4*)(sBl + (arow + 64 * p) * LROW + aq) = b_l[p];
        }
        __syncthreads();

        bf16x8 bh[4], bl[4];
        #pragma unroll
        for (int nf = 0; nf < 4; ++nf) {
            bh[nf] = *(const bf16x8*)(sBh + (w * 64 + nf * 16 + fr) * LROW + kg);
            if constexpr (SPLIT == 3)
                bl[nf] = *(const bf16x8*)(sBl + (w * 64 + nf * 16 + fr) * LROW + kg);
        }
        #pragma unroll
        for (int mf = 0; mf < 4; ++mf) {
            const bf16x8 ah = *(const bf16x8*)(sAh + (mf * 16 + fr) * LROW + kg);
            if constexpr (SPLIT == 3) {
                const bf16x8 al = *(const bf16x8*)(sAl + (mf * 16 + fr) * LROW + kg);
                #pragma unroll
                for (int nf = 0; nf < 4; ++nf) {
                    acc[mf][nf] = __builtin_amdgcn_mfma_f32_16x16x32_bf16(ah, bh[nf], acc[mf][nf], 0, 0, 0);
                    acc[mf][nf] = __builtin_amdgcn_mfma_f32_16x16x32_bf16(ah, bl[nf], acc[mf][nf], 0, 0, 0);
                    acc[mf][nf] = __builtin_amdgcn_mfma_f32_16x16x32_bf16(al, bh[nf], acc[mf][nf], 0, 0, 0);
                }
            } else {
                #pragma unroll
                for (int nf = 0; nf < 4; ++nf)
                    acc[mf][nf] = __builtin_amdgcn_mfma_f32_16x16x32_bf16(ah, bh[nf], acc[mf][nf], 0, 0, 0);
            }
        }
    }

    #pragma unroll
    for (int nf = 0; nf < 4; ++nf) {
        const int nn = ntile + w * 64 + nf * 16 + fr;
        if (nn < N) {
            const float bv = bias ? bias[nn] : 0.f;
            #pragma unroll
            for (int mf = 0; mf < 4; ++mf) {
                #pragma unroll
                for (int rr = 0; rr < 4; ++rr) {
                    const int m = mtile + mf * 16 + (lane >> 4) * 4 + rr;
                    const float v = acc[mf][nf][rr] + bv;
                    if constexpr (CMAP == 1)
                        ((ush*)Cv)[(size_t)m * ldc + nn] = f2bf(v);
                    else
                        ((float*)Cv)[(size_t)m * ldc + nn] = v;
                }
            }
        }
    }
}

// ---------------------------------------------------------------------------
// gemm_gates: 64x64 tile, segmented A (2 segments), split-K via grid.z.
// ---------------------------------------------------------------------------
__global__ __launch_bounds__(256) void gemm_gates(
    const ush* __restrict__ Ah0, const ush* __restrict__ Al0, int lda0, int k0,
    const ush* __restrict__ Ah1, const ush* __restrict__ Al1, int lda1,
    const ush* __restrict__ Wh, const ush* __restrict__ Wl, int ldw,
    float* __restrict__ C, int ldc, long zstride, int kChunk)
{
    __shared__ ush sAh[64 * LROW];
    __shared__ ush sBh[64 * LROW];
    __shared__ ush sAl[64 * LROW];
    __shared__ ush sBl[64 * LROW];

    const int tid = threadIdx.x;
    const int ntile = blockIdx.x * 64;
    const int kStart = blockIdx.z * kChunk;
    const int lane = tid & 63, w = tid >> 6;
    const int lrow = tid >> 2;
    const int lcol = (tid & 3) * 8;
    const int nrow = ntile + lrow;

    f32x4 acc[4];
    #pragma unroll
    for (int f = 0; f < 4; ++f) acc[f] = {0.f, 0.f, 0.f, 0.f};

    const int fr = lane & 15;
    const int kg = (lane >> 4) * 8;

    for (int kb = kStart; kb < kStart + kChunk; kb += 32) {
        const ush *ph, *pl; int lda, loc;
        if (kb < k0) { ph = Ah0; pl = Al0; lda = lda0; loc = kb; }
        else         { ph = Ah1; pl = Al1; lda = lda1; loc = kb - k0; }

        uint4 a_h = *(const uint4*)(ph + (size_t)lrow * lda + loc + lcol);
        uint4 b_h = *(const uint4*)(Wh + (size_t)nrow * ldw + kb + lcol);
        uint4 a_l = *(const uint4*)(pl + (size_t)lrow * lda + loc + lcol);
        uint4 b_l = *(const uint4*)(Wl + (size_t)nrow * ldw + kb + lcol);

        __syncthreads();
        *(uint4*)(sAh + lrow * LROW + lcol) = a_h;
        *(uint4*)(sBh + lrow * LROW + lcol) = b_h;
        *(uint4*)(sAl + lrow * LROW + lcol) = a_l;
        *(uint4*)(sBl + lrow * LROW + lcol) = b_l;
        __syncthreads();

        const bf16x8 bh = *(const bf16x8*)(sBh + (16 * w + fr) * LROW + kg);
        const bf16x8 bl = *(const bf16x8*)(sBl + (16 * w + fr) * LROW + kg);

        #pragma unroll
        for (int f = 0; f < 4; ++f) {
            const bf16x8 ah = *(const bf16x8*)(sAh + (16 * f + fr) * LROW + kg);
            const bf16x8 al = *(const bf16x8*)(sAl + (16 * f + fr) * LROW + kg);
            acc[f] = __builtin_amdgcn_mfma_f32_16x16x32_bf16(ah, bh, acc[f], 0, 0, 0);
            acc[f] = __builtin_amdgcn_mfma_f32_16x16x32_bf16(ah, bl, acc[f], 0, 0, 0);
            acc[f] = __builtin_amdgcn_mfma_f32_16x16x32_bf16(al, bh, acc[f], 0, 0, 0);
        }
    }

    const int n = ntile + 16 * w + (lane & 15);
    float* Cz = C + (size_t)blockIdx.z * zstride;
    #pragma unroll
    for (int f = 0; f < 4; ++f)
        #pragma unroll
        for (int rr = 0; rr < 4; ++rr) {
            const int m = 16 * f + (lane >> 4) * 4 + rr;
            Cz[(size_t)m * ldc + n] = acc[f][rr];
        }
}

// fused feats pass: fbh (bf16) + per-(b,f) mean -> mh/ml. block (fs, b).
__global__ __launch_bounds__(256) void prep_feats(
    const float* __restrict__ feats, ush* __restrict__ fbh,
    ush* __restrict__ mh, ush* __restrict__ ml)
{
    const int fs = blockIdx.x;
    const int b  = blockIdx.y;
    const int f = fs * 512 + threadIdx.x * 2;
    const float2* fp = (const float2*)(feats + (size_t)b * R_ * F_ + f);
    ush* fo = fbh + (size_t)b * R_ * F_ + f;
    float sx = 0.f, sy = 0.f;
    for (int r = 0; r < R_; ++r) {
        const float2 v = fp[(size_t)r * (F_ / 2)];
        sx += v.x; sy += v.y;
        ushort2 u; u.x = f2bf(v.x); u.y = f2bf(v.y);
        *(ushort2*)(fo + (size_t)r * F_) = u;
    }
    const float s = 1.f / (float)R_;
    sx *= s; sy *= s;
    const size_t mi = (size_t)b * F_ + f;
    const ush hx = f2bf(sx); mh[mi] = hx;     ml[mi] = f2bf(sx - bf2f(hx));
    const ush hy = f2bf(sy); mh[mi + 1] = hy; ml[mi + 1] = f2bf(sy - bf2f(hy));
}

// gather embeddings -> bf16 hi/lo (B,L,E)
__global__ __launch_bounds__(256) void gather_split(
    const float* __restrict__ emb, const int* __restrict__ cap,
    ush* __restrict__ eh, ush* __restrict__ el)
{
    const int idx = blockIdx.x * 256 + threadIdx.x;
    const int bt = idx >> 7, j = idx & 127;
    const int tok = cap[bt];
    const float4 v = reinterpret_cast<const float4*>(emb)[(size_t)tok * (E_ / 4) + j];
    const float a[4] = {v.x, v.y, v.z, v.w};
    #pragma unroll
    for (int c = 0; c < 4; ++c) {
        const ush hi = f2bf(a[c]);
        eh[idx * 4 + c] = hi;
        el[idx * 4 + c] = f2bf(a[c] - bf2f(hi));
    }
}

// generic fp32 -> bf16 (hi, optional lo)
__global__ __launch_bounds__(256) void split_kernel(
    const float* __restrict__ in, ush* __restrict__ hi, ush* __restrict__ lo, int n4)
{
    for (int i = blockIdx.x * 256 + threadIdx.x; i < n4; i += gridDim.x * 256) {
        const float4 v = reinterpret_cast<const float4*>(in)[i];
        const float a[4] = {v.x, v.y, v.z, v.w};
        #pragma unroll
        for (int c = 0; c < 4; ++c) {
            const ush h = f2bf(a[c]);
            hi[i * 4 + c] = h;
            if (lo) lo[i * 4 + c] = f2bf(a[c] - bf2f(h));
        }
    }
}

// W_ih columns [0:E) -> wx (2048x512); [E:) ++ W_hh -> wg2 (2048x2560); hi/lo
__global__ __launch_bounds__(256) void prep_wih(
    const float* __restrict__ W_ih, const float* __restrict__ W_hh,
    ush* __restrict__ wxh, ush* __restrict__ wxl,
    ush* __restrict__ wg2h, ush* __restrict__ wg2l)
{
    const int nrow = blockIdx.x;
    for (int k = threadIdx.x; k < E_; k += 256) {
        const float v = W_ih[(size_t)nrow * (E_ + F_) + k];
        const ush h = f2bf(v);
        wxh[(size_t)nrow * E_ + k] = h;
        wxl[(size_t)nrow * E_ + k] = f2bf(v - bf2f(h));
    }
    for (int k = threadIdx.x; k < F_ + H_; k += 256) {
        const float v = (k < F_) ? W_ih[(size_t)nrow * (E_ + F_) + E_ + k]
                                 : W_hh[(size_t)nrow * H_ + (k - F_)];
        const ush h = f2bf(v);
        wg2h[(size_t)nrow * (F_ + H_) + k] = h;
        wg2l[(size_t)nrow * (F_ + H_) + k] = f2bf(v - bf2f(h));
    }
}

// transpose W_hidp (A x H) -> whpT (H x A), fp32
__global__ __launch_bounds__(256) void transpose512(
    const float* __restrict__ in, float* __restrict__ out)
{
    const int idx = blockIdx.x * 256 + threadIdx.x;
    const int k = idx >> 9, a = idx & 511;
    out[idx] = in[(size_t)a * 512 + k];
    (void)k;
}

// reduce init GEMM partials: n<512 -> h0 (+split), n>=512 -> c0
__global__ __launch_bounds__(256) void init_reduce(
    const float* __restrict__ initp, const float* __restrict__ b_init_h,
    const float* __restrict__ b_init_c, float* __restrict__ h0f,
    float* __restrict__ c, ush* __restrict__ h_hi, ush* __restrict__ h_lo)
{
    const int idx = blockIdx.x * 256 + threadIdx.x;
    const int b = idx >> 10, n = idx & 1023;
    float s = 0.f;
    #pragma unroll
    for (int z = 0; z < 8; ++z)
        s += initp[(size_t)z * (B_ * 1024) + (size_t)b * 1024 + n];
    if (n < 512) {
        s += b_init_h[n];
        h0f[b * H_ + n] = s;
        const ush hi = f2bf(s);
        h_hi[b * H_ + n] = hi;
        h_lo[b * H_ + n] = f2bf(s - bf2f(hi));
    } else {
        s += b_init_c[n - 512];
        c[b * H_ + (n - 512)] = s;
    }
}

// ---------------------------------------------------------------------------
// step_kernel<ATT>: per-b block, 512 threads.
// Phase A (t>0): LSTM cell from gparts(t-1)+egates(t-1).
// Phase B (ATT): hid_proj -> scores(tanh) -> softmax -> alpha (LDS)
// Phase C (ATT): context from bf16 fbh (4 f per thread), write ctx hi/lo.
// ---------------------------------------------------------------------------
template<bool ATT>
__global__ __launch_bounds__(512) void step_kernel(
    const float* __restrict__ gparts, const float* __restrict__ egates,
    const float* __restrict__ b_ih, const float* __restrict__ b_hh,
    float* __restrict__ c, const float* __restrict__ h0f,
    ush* __restrict__ h_hi, ush* __restrict__ h_lo,
    ush* __restrict__ hall_hi, ush* __restrict__ hall_lo,
    const float* __restrict__ whpT, const float* __restrict__ b_hidp,
    const ush* __restrict__ fpb, const float* __restrict__ W_score,
    const float* __restrict__ b_score, const ush* __restrict__ fbh,
    ush* __restrict__ ctx_hi, ush* __restrict__ ctx_lo,
    float* __restrict__ alph_out, int t)
{
    __shared__ float sh_h[H_];
    __shared__ float sh_hp[A_];
    __shared__ float sh_ws[A_];
    __shared__ float sh_sc[200];
    __shared__ float red[2];
    const int tid = threadIdx.x;
    const int b = blockIdx.x;
    const int n = tid;

    float hh;
    if (t > 0) {
        const float* eg = egates + ((size_t)b * L_ + (t - 1)) * 2048;
        float gi = b_ih[n] + b_hh[n] + eg[n];
        float gf = b_ih[n + 512] + b_hh[n + 512] + eg[n + 512];
        float gg = b_ih[n + 1024] + b_hh[n + 1024] + eg[n + 1024];
        float go = b_ih[n + 1536] + b_hh[n + 1536] + eg[n + 1536];
        #pragma unroll
        for (int z = 0; z < 8; ++z) {
            const float* gz = gparts + (size_t)z * B_ * 2048 + (size_t)b * 2048;
            gi += gz[n]; gf += gz[n + 512]; gg += gz[n + 1024]; go += gz[n + 1536];
        }
        const float cc = fast_sig(gf) * c[b * H_ + n] + fast_sig(gi) * fast_tanh(gg);
        hh = fast_sig(go) * fast_tanh(cc);
        c[b * H_ + n] = cc;
        const ush hi = f2bf(hh);
        const ush lo = f2bf(hh - bf2f(hi));
        h_hi[b * H_ + n] = hi;
        h_lo[b * H_ + n] = lo;
        const size_t hidx = ((size_t)(t - 1) * B_ + b) * H_ + n;
        hall_hi[hidx] = hi;
        hall_lo[hidx] = lo;
    } else {
        hh = h0f[b * H_ + n];
    }
    if constexpr (!ATT) return;

    sh_h[n] = hh;
    sh_ws[n] = W_score[n];
    __syncthreads();

    // hid_proj (coalesced via transposed W_hidp)
    {
        float a0 = 0.f, a1 = 0.f, a2 = 0.f, a3 = 0.f;
        #pragma unroll 4
        for (int k = 0; k < H_; k += 4) {
            a0 = fmaf(sh_h[k + 0], whpT[(size_t)(k + 0) * A_ + tid], a0);
            a1 = fmaf(sh_h[k + 1], whpT[(size_t)(k + 1) * A_ + tid], a1);
            a2 = fmaf(sh_h[k + 2], whpT[(size_t)(k + 2) * A_ + tid], a2);
            a3 = fmaf(sh_h[k + 3], whpT[(size_t)(k + 3) * A_ + tid], a3);
        }
        sh_hp[tid] = (a0 + a1) + (a2 + a3) + b_hidp[tid];
    }
    __syncthreads();

    const int lane = tid & 63, wid = tid >> 6;
    for (int r = wid; r < R_; r += 8) {
        const ushort2* row = reinterpret_cast<const ushort2*>(fpb + ((size_t)b * R_ + r) * A_);
        float acc = 0.f;
        #pragma unroll
        for (int j = 0; j < 4; ++j) {
            const ushort2 u = row[lane + 64 * j];
            const int a = 2 * (lane + 64 * j);
            acc += fast_tanh(bf2f(u.x) + sh_hp[a]) * sh_ws[a];
            acc += fast_tanh(bf2f(u.y) + sh_hp[a + 1]) * sh_ws[a + 1];
        }
        for (int off = 32; off > 0; off >>= 1) acc += __shfl_down(acc, off);
        if (lane == 0) sh_sc[r] = acc + b_score[0];
    }
    __syncthreads();

    if (tid < 64) {
        float m = -1e30f;
        for (int r = tid; r < R_; r += 64) m = fmaxf(m, sh_sc[r]);
        for (int off = 32; off > 0; off >>= 1) m = fmaxf(m, __shfl_xor(m, off));
        float s = 0.f;
        for (int r = tid; r < R_; r += 64) s += __expf(sh_sc[r] - m);
        for (int off = 32; off > 0; off >>= 1) s += __shfl_xor(s, off);
        if (tid == 0) { red[0] = m; red[1] = 1.f / s; }
    }
    __syncthreads();
    const float m = red[0], is = red[1];
    if (tid < R_) {
        const float av = __expf(sh_sc[tid] - m) * is;
        sh_sc[tid] = av;
        alph_out[((size_t)b * L_ + t) * R_ + tid] = av;
    }
    __syncthreads();

    // ---- context: 4 f per thread, fp32 accumulate over bf16 feats ----
    {
        const int f0 = tid << 2;
        const ush* fp2 = fbh + (size_t)b * R_ * F_ + f0;
        float c0 = 0.f, c1 = 0.f, c2 = 0.f, c3 = 0.f;
        #pragma unroll 2
        for (int r = 0; r < R_; ++r) {
            const float a = sh_sc[r];
            const ushort4 u = *(const ushort4*)(fp2 + (size_t)r * F_);
            c0 = fmaf(a, bf2f(u.x), c0);
            c1 = fmaf(a, bf2f(u.y), c1);
            c2 = fmaf(a, bf2f(u.z), c2);
            c3 = fmaf(a, bf2f(u.w), c3);
        }
        ushort4 hi4, lo4;
        hi4.x = f2bf(c0); lo4.x = f2bf(c0 - bf2f(hi4.x));
        hi4.y = f2bf(c1); lo4.y = f2bf(c1 - bf2f(hi4.y));
        hi4.z = f2bf(c2); lo4.z = f2bf(c2 - bf2f(hi4.z));
        hi4.w = f2bf(c3); lo4.w = f2bf(c3 - bf2f(hi4.w));
        const size_t ci = (size_t)b * F_ + f0;
        *(ushort4*)(ctx_hi + ci) = hi4;
        *(ushort4*)(ctx_lo + ci) = lo4;
    }
}

extern "C" void kernel_launch(void* const* d_in, const int* in_sizes, int n_in,
                              void* d_out, int out_size, void* d_ws, size_t ws_size,
                              hipStream_t stream)
{
    const float* feats    = (const float*)d_in[0];
    const int*   cap      = (const int*)  d_in[1];
    const float* emb      = (const float*)d_in[2];
    const float* W_init_h = (const float*)d_in[3];
    const float* b_init_h = (const float*)d_in[4];
    const float* W_init_c = (const float*)d_in[5];
    const float* b_init_c = (const float*)d_in[6];
    const float* W_ih     = (const float*)d_in[7];
    const float* b_ih     = (const float*)d_in[8];
    const float* W_hh     = (const float*)d_in[9];
    const float* b_hh     = (const float*)d_in[10];
    const float* W_featp  = (const float*)d_in[11];
    const float* b_featp  = (const float*)d_in[12];
    const float* W_hidp   = (const float*)d_in[13];
    const float* b_hidp   = (const float*)d_in[14];
    const float* W_score  = (const float*)d_in[15];
    const float* b_score  = (const float*)d_in[16];
    const float* W_out    = (const float*)d_in[17];
    const float* b_out    = (const float*)d_in[18];

    float* pred     = (float*)d_out;                          // (B,L,V)
    float* alph_out = pred + (size_t)B_ * L_ * V_;            // (B,L,R)

    char* p = (char*)d_ws;
    auto alloc = [&](size_t bytes) { char* q = p; p += (bytes + 255) & ~(size_t)255; return q; };

    ush*   fpb    = (ush*)  alloc((size_t)B_ * R_ * A_ * 2);
    ush*   eh     = (ush*)  alloc((size_t)B_ * L_ * E_ * 2);
    ush*   el     = (ush*)  alloc((size_t)B_ * L_ * E_ * 2);
    ush*   mh     = (ush*)  alloc((size_t)B_ * F_ * 2);
    ush*   ml     = (ush*)  alloc((size_t)B_ * F_ * 2);
    ush*   fbh    = (ush*)  alloc((size_t)B_ * R_ * F_ * 2);
    ush*   wfp_h  = (ush*)  alloc((size_t)A_ * F_ * 2);
    ush*   wiH    = (ush*)  alloc((size_t)1024 * F_ * 2);
    ush*   wiL    = (ush*)  alloc((size_t)1024 * F_ * 2);
    ush*   wxh    = (ush*)  alloc((size_t)2048 * E_ * 2);
    ush*   wxl    = (ush*)  alloc((size_t)2048 * E_ * 2);
    ush*   wg2h   = (ush*)  alloc((size_t)2048 * (F_ + H_) * 2);
    ush*   wg2l   = (ush*)  alloc((size_t)2048 * (F_ + H_) * 2);
    ush*   woh    = (ush*)  alloc((size_t)V_ * H_ * 2);
    ush*   wol    = (ush*)  alloc((size_t)V_ * H_ * 2);
    float* whpT   = (float*)alloc((size_t)H_ * A_ * 4);
    float* egates = (float*)alloc((size_t)B_ * L_ * 2048 * 4);
    float* h0f    = (float*)alloc((size_t)B_ * H_ * 4);
    float* c      = (float*)alloc((size_t)B_ * H_ * 4);
    ush*   h_hi   = (ush*)  alloc((size_t)B_ * H_ * 2);
    ush*   h_lo   = (ush*)  alloc((size_t)B_ * H_ * 2);
    ush*   hallh  = (ush*)  alloc((size_t)L_ * B_ * H_ * 2);
    ush*   halll  = (ush*)  alloc((size_t)L_ * B_ * H_ * 2);
    ush*   ctx_hi = (ush*)  alloc((size_t)B_ * F_ * 2);
    ush*   ctx_lo = (ush*)  alloc((size_t)B_ * F_ * 2);
    float* gparts = (float*)alloc((size_t)8 * B_ * 2048 * 4);
    float* initp  = (float*)alloc((size_t)8 * B_ * 1024 * 4);

    // ---- one-time prep ----
    prep_feats<<<dim3(4, B_), 256, 0, stream>>>(feats, fbh, mh, ml);
    gather_split<<<768, 256, 0, stream>>>(emb, cap, eh, el);
    split_kernel<<<2048, 256, 0, stream>>>(W_out, woh, wol, V_ * H_ / 4);
    split_kernel<<<512, 256, 0, stream>>>(W_init_h, wiH, wiL, H_ * F_ / 4);
    split_kernel<<<512, 256, 0, stream>>>(W_init_c, wiH + (size_t)512 * F_,
                                          wiL + (size_t)512 * F_, H_ * F_ / 4);
    split_kernel<<<512, 256, 0, stream>>>(W_featp, wfp_h, nullptr, A_ * F_ / 4);
    prep_wih<<<2048, 256, 0, stream>>>(W_ih, W_hh, wxh, wxl, wg2h, wg2l);
    transpose512<<<1024, 256, 0, stream>>>(W_hidp, whpT);

    // h0/c0 init: M=64, N=1024 (stacked), K=2048, split-K=8
    gemm_gates<<<dim3(16, 1, 8), 256, 0, stream>>>(
        mh, ml, F_, F_,
        mh, ml, F_,
        wiH, wiL, F_,
        initp, 1024, (long)B_ * 1024, F_ / 8);
    init_reduce<<<256, 256, 0, stream>>>(initp, b_init_h, b_init_c, h0f, c, h_hi, h_lo);

    // feat_proj (SPLIT=1, bf16 out): M=12544, N=512 -> grid(196,2), 392 blocks
    gemm_big<1, 1, true><<<dim3(196, 2), 256, 0, stream>>>(
        fbh, nullptr, F_, wfp_h, nullptr, F_, b_featp, fpb, A_, A_, F_);

    // emb gate part for ALL steps (SPLIT=3): M=1536, N=2048 -> grid(24,8)
    gemm_big<3, 0, false><<<dim3(24, 8), 256, 0, stream>>>(
        eh, el, E_, wxh, wxl, E_, nullptr, egates, 2048, 2048, E_);

    // ---- sequential decode: 2 kernels per step ----
    for (int t = 0; t < L_; ++t) {
        step_kernel<true><<<B_, 512, 0, stream>>>(
            gparts, egates, b_ih, b_hh, c, h0f, h_hi, h_lo, hallh, halll,
            whpT, b_hidp, fpb, W_score, b_score, fbh, ctx_hi, ctx_lo,
            alph_out, t);

        gemm_gates<<<dim3(32, 1, 8), 256, 0, stream>>>(
            ctx_hi, ctx_lo, F_, F_,
            h_hi, h_lo, H_,
            wg2h, wg2l, F_ + H_,
            gparts, 4 * H_, (long)B_ * 4 * H_, (F_ + H_) / 8);
    }

    // final cell: h_L -> hall[L-1]
    step_kernel<false><<<B_, 512, 0, stream>>>(
        gparts, egates, b_ih, b_hh, c, h0f, h_hi, h_lo, hallh, halll,
        whpT, b_hidp, fpb, W_score, b_score, fbh, ctx_hi, ctx_lo,
        alph_out, L_);

    // predictions for ALL steps (SPLIT=3): M=1536 -> 12 tiles of 128, N=12000
    gemm_big128<3, 2, false><<<dim3(12, 47), 512, 0, stream>>>(
        hallh, halll, H_, woh, wol, H_, b_out, pred, 0, V_, H_);
}

// Round 9
// 2100.043 us; speedup vs baseline: 1.0995x; 1.0995x over previous
//
#include <hip/hip_runtime.h>

#define B_ 64
#define R_ 196
#define F_ 2048
#define E_ 512
#define H_ 512
#define A_ 512
#define V_ 12000
#define L_ 24

typedef __attribute__((ext_vector_type(8))) short bf16x8;
typedef __attribute__((ext_vector_type(4))) float f32x4;
typedef unsigned short ush;

__device__ __forceinline__ float fast_tanh(float x) {
    float t = __expf(2.f * x);
    return 1.f - 2.f / (t + 1.f);
}
__device__ __forceinline__ float fast_sig(float x) {
    return 1.f / (1.f + __expf(-x));
}
__device__ __forceinline__ ush f2bf(float x) {
    unsigned int u = __float_as_uint(x);
    return (ush)((u + 0x7fffu + ((u >> 16) & 1u)) >> 16);
}
__device__ __forceinline__ float bf2f(ush b) {
    return __uint_as_float(((unsigned int)b) << 16);
}

#define LROW 40   // LDS row stride (32 k-elems + 8 pad)

// ---------------------------------------------------------------------------
// gemm_big128: C = A @ W^T (+bias). Tile 128M x 256N, BK=32, 512 threads
// (8 waves: 2 m-waves x 4 n-waves). Pred GEMM (564 blocks; WRITE-amp fixed).
// Bijective XCD-chunked swizzle. SPLIT=3: (hi,lo) bf16x2, 3 MFMAs.
// CMAP=2: pred layout C[(m&63)*L*V + (m>>6)*V + n] fp32 NT stores.
// ---------------------------------------------------------------------------
template<int SPLIT, int CMAP, bool NFAST>
__global__ __launch_bounds__(512) void gemm_big128(
    const ush* __restrict__ Ah, const ush* __restrict__ Al, int lda,
    const ush* __restrict__ Wh, const ush* __restrict__ Wl, int ldw,
    const float* __restrict__ bias, void* __restrict__ Cv,
    int ldc, int N, int K)
{
    constexpr int SMEM_BYTES = (SPLIT == 3) ? 61440 : 30720;
    __shared__ __align__(16) char smem[SMEM_BYTES];
    ush* sAh = (ush*)smem;                    // 128 x LROW = 10240 B
    ush* sBh = (ush*)(smem + 10240);          // 256 x LROW = 20480 B
    ush* sAl = (ush*)(smem + 30720);
    ush* sBl = (ush*)(smem + 40960);

    const int tid = threadIdx.x;
    const int lane = tid & 63, w = tid >> 6;
    const int mw = w >> 2, nw = w & 3;

    const int nbx = gridDim.x, nby = gridDim.y;
    const int nwg = nbx * nby;
    const int orig = blockIdx.x + nbx * blockIdx.y;
    const int q = nwg >> 3, r = nwg & 7;
    const int xcd = orig & 7, idx = orig >> 3;
    const int lin = (xcd < r ? xcd * (q + 1) : r * (q + 1) + (xcd - r) * q) + idx;
    int bx, by;
    if constexpr (NFAST) { by = lin % nby; bx = lin / nby; }
    else                 { bx = lin % nbx; by = lin / nbx; }
    const int mtile = bx * 128;
    const int ntile = by * 256;

    const int fr = lane & 15, kg = (lane >> 4) * 8;
    const int arow = tid >> 2, aq = (tid & 3) * 8;

    f32x4 acc[4][4];
    #pragma unroll
    for (int mf = 0; mf < 4; ++mf)
        #pragma unroll
        for (int nf = 0; nf < 4; ++nf) acc[mf][nf] = {0.f, 0.f, 0.f, 0.f};

    const uint4 zv = make_uint4(0u, 0u, 0u, 0u);

    for (int kb = 0; kb < K; kb += 32) {
        uint4 a_h = *(const uint4*)(Ah + (size_t)(mtile + arow) * lda + kb + aq);
        uint4 a_l;
        uint4 b_h[2], b_l[2];
        #pragma unroll
        for (int p = 0; p < 2; ++p) {
            const int row = ntile + arow + 128 * p;
            b_h[p] = (row < N) ? *(const uint4*)(Wh + (size_t)row * ldw + kb + aq) : zv;
        }
        if constexpr (SPLIT == 3) {
            a_l = *(const uint4*)(Al + (size_t)(mtile + arow) * lda + kb + aq);
            #pragma unroll
            for (int p = 0; p < 2; ++p) {
                const int row = ntile + arow + 128 * p;
                b_l[p] = (row < N) ? *(const uint4*)(Wl + (size_t)row * ldw + kb + aq) : zv;
            }
        }

        __syncthreads();
        *(uint4*)(sAh + arow * LROW + aq) = a_h;
        #pragma unroll
        for (int p = 0; p < 2; ++p)
            *(uint4*)(sBh + (arow + 128 * p) * LROW + aq) = b_h[p];
        if constexpr (SPLIT == 3) {
            *(uint4*)(sAl + arow * LROW + aq) = a_l;
            #pragma unroll
            for (int p = 0; p < 2; ++p)
                *(uint4*)(sBl + (arow + 128 * p) * LROW + aq) = b_l[p];
        }
        __syncthreads();

        bf16x8 bh[4], bl[4];
        #pragma unroll
        for (int nf = 0; nf < 4; ++nf) {
            bh[nf] = *(const bf16x8*)(sBh + (nw * 64 + nf * 16 + fr) * LROW + kg);
            if constexpr (SPLIT == 3)
                bl[nf] = *(const bf16x8*)(sBl + (nw * 64 + nf * 16 + fr) * LROW + kg);
        }
        #pragma unroll
        for (int mf = 0; mf < 4; ++mf) {
            const bf16x8 ah = *(const bf16x8*)(sAh + (mw * 64 + mf * 16 + fr) * LROW + kg);
            if constexpr (SPLIT == 3) {
                const bf16x8 al = *(const bf16x8*)(sAl + (mw * 64 + mf * 16 + fr) * LROW + kg);
                #pragma unroll
                for (int nf = 0; nf < 4; ++nf) {
                    acc[mf][nf] = __builtin_amdgcn_mfma_f32_16x16x32_bf16(ah, bh[nf], acc[mf][nf], 0, 0, 0);
                    acc[mf][nf] = __builtin_amdgcn_mfma_f32_16x16x32_bf16(ah, bl[nf], acc[mf][nf], 0, 0, 0);
                    acc[mf][nf] = __builtin_amdgcn_mfma_f32_16x16x32_bf16(al, bh[nf], acc[mf][nf], 0, 0, 0);
                }
            } else {
                #pragma unroll
                for (int nf = 0; nf < 4; ++nf)
                    acc[mf][nf] = __builtin_amdgcn_mfma_f32_16x16x32_bf16(ah, bh[nf], acc[mf][nf], 0, 0, 0);
            }
        }
    }

    #pragma unroll
    for (int nf = 0; nf < 4; ++nf) {
        const int nn = ntile + nw * 64 + nf * 16 + fr;
        if (nn < N) {
            const float bv = bias ? bias[nn] : 0.f;
            #pragma unroll
            for (int mf = 0; mf < 4; ++mf) {
                #pragma unroll
                for (int rr = 0; rr < 4; ++rr) {
                    const int m = mtile + mw * 64 + mf * 16 + (lane >> 4) * 4 + rr;
                    const float v = acc[mf][nf][rr] + bv;
                    if constexpr (CMAP == 1)
                        ((ush*)Cv)[(size_t)m * ldc + nn] = f2bf(v);
                    else if constexpr (CMAP == 2) {
                        float* dst = (float*)Cv + (size_t)(m & 63) * (L_ * V_)
                                   + (size_t)(m >> 6) * V_ + nn;
                        __builtin_nontemporal_store(v, dst);
                    } else
                        ((float*)Cv)[(size_t)m * ldc + nn] = v;
                }
            }
        }
    }
}

// ---------------------------------------------------------------------------
// gemm_big: 64M x (64*NF)N tile, 256 threads (4 waves, NF 16-col frags each).
// NF=2 -> 128N tile (more blocks, better balance); NF=4 -> 256N tile.
// ---------------------------------------------------------------------------
template<int SPLIT, int CMAP, bool NFAST, int NF>
__global__ __launch_bounds__(256) void gemm_big(
    const ush* __restrict__ Ah, const ush* __restrict__ Al, int lda,
    const ush* __restrict__ Wh, const ush* __restrict__ Wl, int ldw,
    const float* __restrict__ bias, void* __restrict__ Cv,
    int ldc, int N, int K)
{
    constexpr int ABYTES = 64 * LROW * 2;
    constexpr int BBYTES = 64 * NF * LROW * 2;
    constexpr int SMEM_BYTES = (SPLIT == 3) ? 2 * (ABYTES + BBYTES) : (ABYTES + BBYTES);
    __shared__ __align__(16) char smem[SMEM_BYTES];
    ush* sAh = (ush*)smem;
    ush* sBh = (ush*)(smem + ABYTES);
    ush* sAl = (ush*)(smem + ABYTES + BBYTES);
    ush* sBl = (ush*)(smem + 2 * ABYTES + BBYTES);

    const int tid = threadIdx.x;
    const int lane = tid & 63, w = tid >> 6;

    const int nbx = gridDim.x, nby = gridDim.y;
    const int nwg = nbx * nby;
    int lin = blockIdx.x + nbx * blockIdx.y;
    if ((nwg & 7) == 0) {
        const int q = nwg >> 3;
        lin = (lin & 7) * q + (lin >> 3);
    }
    int bx, by;
    if constexpr (NFAST) { by = lin % nby; bx = lin / nby; }
    else                 { bx = lin % nbx; by = lin / nbx; }
    const int mtile = bx * 64;
    const int ntile = by * (64 * NF);

    const int fr = lane & 15, kg = (lane >> 4) * 8;
    const int arow = tid >> 2, aq = (tid & 3) * 8;

    f32x4 acc[4][NF];
    #pragma unroll
    for (int mf = 0; mf < 4; ++mf)
        #pragma unroll
        for (int nf = 0; nf < NF; ++nf) acc[mf][nf] = {0.f, 0.f, 0.f, 0.f};

    const uint4 zv = make_uint4(0u, 0u, 0u, 0u);

    for (int kb = 0; kb < K; kb += 32) {
        uint4 a_h = *(const uint4*)(Ah + (size_t)(mtile + arow) * lda + kb + aq);
        uint4 a_l;
        uint4 b_h[NF], b_l[NF];
        #pragma unroll
        for (int p = 0; p < NF; ++p) {
            const int row = ntile + arow + 64 * p;
            b_h[p] = (row < N) ? *(const uint4*)(Wh + (size_t)row * ldw + kb + aq) : zv;
        }
        if constexpr (SPLIT == 3) {
            a_l = *(const uint4*)(Al + (size_t)(mtile + arow) * lda + kb + aq);
            #pragma unroll
            for (int p = 0; p < NF; ++p) {
                const int row = ntile + arow + 64 * p;
                b_l[p] = (row < N) ? *(const uint4*)(Wl + (size_t)row * ldw + kb + aq) : zv;
            }
        }

        __syncthreads();
        *(uint4*)(sAh + arow * LROW + aq) = a_h;
        #pragma unroll
        for (int p = 0; p < NF; ++p)
            *(uint4*)(sBh + (arow + 64 * p) * LROW + aq) = b_h[p];
        if constexpr (SPLIT == 3) {
            *(uint4*)(sAl + arow * LROW + aq) = a_l;
            #pragma unroll
            for (int p = 0; p < NF; ++p)
                *(uint4*)(sBl + (arow + 64 * p) * LROW + aq) = b_l[p];
        }
        __syncthreads();

        bf16x8 bh[NF], bl[NF];
        #pragma unroll
        for (int nf = 0; nf < NF; ++nf) {
            bh[nf] = *(const bf16x8*)(sBh + (w * (16 * NF) + nf * 16 + fr) * LROW + kg);
            if constexpr (SPLIT == 3)
                bl[nf] = *(const bf16x8*)(sBl + (w * (16 * NF) + nf * 16 + fr) * LROW + kg);
        }
        #pragma unroll
        for (int mf = 0; mf < 4; ++mf) {
            const bf16x8 ah = *(const bf16x8*)(sAh + (mf * 16 + fr) * LROW + kg);
            if constexpr (SPLIT == 3) {
                const bf16x8 al = *(const bf16x8*)(sAl + (mf * 16 + fr) * LROW + kg);
                #pragma unroll
                for (int nf = 0; nf < NF; ++nf) {
                    acc[mf][nf] = __builtin_amdgcn_mfma_f32_16x16x32_bf16(ah, bh[nf], acc[mf][nf], 0, 0, 0);
                    acc[mf][nf] = __builtin_amdgcn_mfma_f32_16x16x32_bf16(ah, bl[nf], acc[mf][nf], 0, 0, 0);
                    acc[mf][nf] = __builtin_amdgcn_mfma_f32_16x16x32_bf16(al, bh[nf], acc[mf][nf], 0, 0, 0);
                }
            } else {
                #pragma unroll
                for (int nf = 0; nf < NF; ++nf)
                    acc[mf][nf] = __builtin_amdgcn_mfma_f32_16x16x32_bf16(ah, bh[nf], acc[mf][nf], 0, 0, 0);
            }
        }
    }

    #pragma unroll
    for (int nf = 0; nf < NF; ++nf) {
        const int nn = ntile + w * (16 * NF) + nf * 16 + fr;
        if (nn < N) {
            const float bv = bias ? bias[nn] : 0.f;
            #pragma unroll
            for (int mf = 0; mf < 4; ++mf) {
                #pragma unroll
                for (int rr = 0; rr < 4; ++rr) {
                    const int m = mtile + mf * 16 + (lane >> 4) * 4 + rr;
                    const float v = acc[mf][nf][rr] + bv;
                    if constexpr (CMAP == 1)
                        ((ush*)Cv)[(size_t)m * ldc + nn] = f2bf(v);
                    else
                        ((float*)Cv)[(size_t)m * ldc + nn] = v;
                }
            }
        }
    }
}

// ---------------------------------------------------------------------------
// gemm_gates: 64x64 tile, segmented A (2 segments), split-K via grid.z.
// ---------------------------------------------------------------------------
__global__ __launch_bounds__(256) void gemm_gates(
    const ush* __restrict__ Ah0, const ush* __restrict__ Al0, int lda0, int k0,
    const ush* __restrict__ Ah1, const ush* __restrict__ Al1, int lda1,
    const ush* __restrict__ Wh, const ush* __restrict__ Wl, int ldw,
    float* __restrict__ C, int ldc, long zstride, int kChunk)
{
    __shared__ ush sAh[64 * LROW];
    __shared__ ush sBh[64 * LROW];
    __shared__ ush sAl[64 * LROW];
    __shared__ ush sBl[64 * LROW];

    const int tid = threadIdx.x;
    const int ntile = blockIdx.x * 64;
    const int kStart = blockIdx.z * kChunk;
    const int lane = tid & 63, w = tid >> 6;
    const int lrow = tid >> 2;
    const int lcol = (tid & 3) * 8;
    const int nrow = ntile + lrow;

    f32x4 acc[4];
    #pragma unroll
    for (int f = 0; f < 4; ++f) acc[f] = {0.f, 0.f, 0.f, 0.f};

    const int fr = lane & 15;
    const int kg = (lane >> 4) * 8;

    for (int kb = kStart; kb < kStart + kChunk; kb += 32) {
        const ush *ph, *pl; int lda, loc;
        if (kb < k0) { ph = Ah0; pl = Al0; lda = lda0; loc = kb; }
        else         { ph = Ah1; pl = Al1; lda = lda1; loc = kb - k0; }

        uint4 a_h = *(const uint4*)(ph + (size_t)lrow * lda + loc + lcol);
        uint4 b_h = *(const uint4*)(Wh + (size_t)nrow * ldw + kb + lcol);
        uint4 a_l = *(const uint4*)(pl + (size_t)lrow * lda + loc + lcol);
        uint4 b_l = *(const uint4*)(Wl + (size_t)nrow * ldw + kb + lcol);

        __syncthreads();
        *(uint4*)(sAh + lrow * LROW + lcol) = a_h;
        *(uint4*)(sBh + lrow * LROW + lcol) = b_h;
        *(uint4*)(sAl + lrow * LROW + lcol) = a_l;
        *(uint4*)(sBl + lrow * LROW + lcol) = b_l;
        __syncthreads();

        const bf16x8 bh = *(const bf16x8*)(sBh + (16 * w + fr) * LROW + kg);
        const bf16x8 bl = *(const bf16x8*)(sBl + (16 * w + fr) * LROW + kg);

        #pragma unroll
        for (int f = 0; f < 4; ++f) {
            const bf16x8 ah = *(const bf16x8*)(sAh + (16 * f + fr) * LROW + kg);
            const bf16x8 al = *(const bf16x8*)(sAl + (16 * f + fr) * LROW + kg);
            acc[f] = __builtin_amdgcn_mfma_f32_16x16x32_bf16(ah, bh, acc[f], 0, 0, 0);
            acc[f] = __builtin_amdgcn_mfma_f32_16x16x32_bf16(ah, bl, acc[f], 0, 0, 0);
            acc[f] = __builtin_amdgcn_mfma_f32_16x16x32_bf16(al, bh, acc[f], 0, 0, 0);
        }
    }

    const int n = ntile + 16 * w + (lane & 15);
    float* Cz = C + (size_t)blockIdx.z * zstride;
    #pragma unroll
    for (int f = 0; f < 4; ++f)
        #pragma unroll
        for (int rr = 0; rr < 4; ++rr) {
            const int m = 16 * f + (lane >> 4) * 4 + rr;
            Cz[(size_t)m * ldc + n] = acc[f][rr];
        }
}

// fused feats pass: fbh (bf16) + per-(b,f) mean -> mh/ml. block (fs, b).
__global__ __launch_bounds__(256) void prep_feats(
    const float* __restrict__ feats, ush* __restrict__ fbh,
    ush* __restrict__ mh, ush* __restrict__ ml)
{
    const int fs = blockIdx.x;
    const int b  = blockIdx.y;
    const int f = fs * 512 + threadIdx.x * 2;
    const float2* fp = (const float2*)(feats + (size_t)b * R_ * F_ + f);
    ush* fo = fbh + (size_t)b * R_ * F_ + f;
    float sx = 0.f, sy = 0.f;
    for (int r = 0; r < R_; ++r) {
        const float2 v = fp[(size_t)r * (F_ / 2)];
        sx += v.x; sy += v.y;
        ushort2 u; u.x = f2bf(v.x); u.y = f2bf(v.y);
        *(ushort2*)(fo + (size_t)r * F_) = u;
    }
    const float s = 1.f / (float)R_;
    sx *= s; sy *= s;
    const size_t mi = (size_t)b * F_ + f;
    const ush hx = f2bf(sx); mh[mi] = hx;     ml[mi] = f2bf(sx - bf2f(hx));
    const ush hy = f2bf(sy); mh[mi + 1] = hy; ml[mi + 1] = f2bf(sy - bf2f(hy));
}

// gather embeddings -> bf16 hi/lo (B,L,E)
__global__ __launch_bounds__(256) void gather_split(
    const float* __restrict__ emb, const int* __restrict__ cap,
    ush* __restrict__ eh, ush* __restrict__ el)
{
    const int idx = blockIdx.x * 256 + threadIdx.x;
    const int bt = idx >> 7, j = idx & 127;
    const int tok = cap[bt];
    const float4 v = reinterpret_cast<const float4*>(emb)[(size_t)tok * (E_ / 4) + j];
    const float a[4] = {v.x, v.y, v.z, v.w};
    #pragma unroll
    for (int c = 0; c < 4; ++c) {
        const ush hi = f2bf(a[c]);
        eh[idx * 4 + c] = hi;
        el[idx * 4 + c] = f2bf(a[c] - bf2f(hi));
    }
}

// generic fp32 -> bf16 (hi, optional lo)
__global__ __launch_bounds__(256) void split_kernel(
    const float* __restrict__ in, ush* __restrict__ hi, ush* __restrict__ lo, int n4)
{
    for (int i = blockIdx.x * 256 + threadIdx.x; i < n4; i += gridDim.x * 256) {
        const float4 v = reinterpret_cast<const float4*>(in)[i];
        const float a[4] = {v.x, v.y, v.z, v.w};
        #pragma unroll
        for (int c = 0; c < 4; ++c) {
            const ush h = f2bf(a[c]);
            hi[i * 4 + c] = h;
            if (lo) lo[i * 4 + c] = f2bf(a[c] - bf2f(h));
        }
    }
}

// W_ih columns [0:E) -> wx (2048x512); [E:) ++ W_hh -> wg2 (2048x2560); hi/lo
__global__ __launch_bounds__(256) void prep_wih(
    const float* __restrict__ W_ih, const float* __restrict__ W_hh,
    ush* __restrict__ wxh, ush* __restrict__ wxl,
    ush* __restrict__ wg2h, ush* __restrict__ wg2l)
{
    const int nrow = blockIdx.x;
    for (int k = threadIdx.x; k < E_; k += 256) {
        const float v = W_ih[(size_t)nrow * (E_ + F_) + k];
        const ush h = f2bf(v);
        wxh[(size_t)nrow * E_ + k] = h;
        wxl[(size_t)nrow * E_ + k] = f2bf(v - bf2f(h));
    }
    for (int k = threadIdx.x; k < F_ + H_; k += 256) {
        const float v = (k < F_) ? W_ih[(size_t)nrow * (E_ + F_) + E_ + k]
                                 : W_hh[(size_t)nrow * H_ + (k - F_)];
        const ush h = f2bf(v);
        wg2h[(size_t)nrow * (F_ + H_) + k] = h;
        wg2l[(size_t)nrow * (F_ + H_) + k] = f2bf(v - bf2f(h));
    }
}

// transpose W_hidp (A x H) -> whpT (H x A), fp32
__global__ __launch_bounds__(256) void transpose512(
    const float* __restrict__ in, float* __restrict__ out)
{
    const int idx = blockIdx.x * 256 + threadIdx.x;
    const int k = idx >> 9, a = idx & 511;
    out[idx] = in[(size_t)a * 512 + k];
    (void)k;
}

// reduce init GEMM partials: n<512 -> h0 (+split), n>=512 -> c0
__global__ __launch_bounds__(256) void init_reduce(
    const float* __restrict__ initp, const float* __restrict__ b_init_h,
    const float* __restrict__ b_init_c, float* __restrict__ h0f,
    float* __restrict__ c, ush* __restrict__ h_hi, ush* __restrict__ h_lo)
{
    const int idx = blockIdx.x * 256 + threadIdx.x;
    const int b = idx >> 10, n = idx & 1023;
    float s = 0.f;
    #pragma unroll
    for (int z = 0; z < 8; ++z)
        s += initp[(size_t)z * (B_ * 1024) + (size_t)b * 1024 + n];
    if (n < 512) {
        s += b_init_h[n];
        h0f[b * H_ + n] = s;
        const ush hi = f2bf(s);
        h_hi[b * H_ + n] = hi;
        h_lo[b * H_ + n] = f2bf(s - bf2f(hi));
    } else {
        s += b_init_c[n - 512];
        c[b * H_ + (n - 512)] = s;
    }
}

// ---------------------------------------------------------------------------
// step_kernel<ATT>: per-b block, 512 threads. Cell (t>0) + attention->alpha.
// ---------------------------------------------------------------------------
template<bool ATT>
__global__ __launch_bounds__(512) void step_kernel(
    const float* __restrict__ gparts, const float* __restrict__ egates,
    const float* __restrict__ b_ih, const float* __restrict__ b_hh,
    float* __restrict__ c, const float* __restrict__ h0f,
    ush* __restrict__ h_hi, ush* __restrict__ h_lo,
    ush* __restrict__ hall_hi, ush* __restrict__ hall_lo,
    const float* __restrict__ whpT, const float* __restrict__ b_hidp,
    const ush* __restrict__ fpb, const float* __restrict__ W_score,
    const float* __restrict__ b_score,
    float* __restrict__ alpha, float* __restrict__ alph_out, int t)
{
    __shared__ float sh_h[H_];
    __shared__ float sh_hp[A_];
    __shared__ float sh_ws[A_];
    __shared__ float sh_sc[200];
    __shared__ float red[2];
    const int tid = threadIdx.x;
    const int b = blockIdx.x;
    const int n = tid;

    float hh;
    if (t > 0) {
        const float* eg = egates + ((size_t)b * L_ + (t - 1)) * 2048;
        float gi = b_ih[n] + b_hh[n] + eg[n];
        float gf = b_ih[n + 512] + b_hh[n + 512] + eg[n + 512];
        float gg = b_ih[n + 1024] + b_hh[n + 1024] + eg[n + 1024];
        float go = b_ih[n + 1536] + b_hh[n + 1536] + eg[n + 1536];
        #pragma unroll
        for (int z = 0; z < 8; ++z) {
            const float* gz = gparts + (size_t)z * B_ * 2048 + (size_t)b * 2048;
            gi += gz[n]; gf += gz[n + 512]; gg += gz[n + 1024]; go += gz[n + 1536];
        }
        const float cc = fast_sig(gf) * c[b * H_ + n] + fast_sig(gi) * fast_tanh(gg);
        hh = fast_sig(go) * fast_tanh(cc);
        c[b * H_ + n] = cc;
        const ush hi = f2bf(hh);
        const ush lo = f2bf(hh - bf2f(hi));
        h_hi[b * H_ + n] = hi;
        h_lo[b * H_ + n] = lo;
        const size_t hidx = ((size_t)(t - 1) * B_ + b) * H_ + n;
        hall_hi[hidx] = hi;
        hall_lo[hidx] = lo;
    } else {
        hh = h0f[b * H_ + n];
    }
    if constexpr (!ATT) return;

    sh_h[n] = hh;
    sh_ws[n] = W_score[n];
    __syncthreads();

    // hid_proj (coalesced via transposed W_hidp)
    {
        float a0 = 0.f, a1 = 0.f, a2 = 0.f, a3 = 0.f;
        #pragma unroll 4
        for (int k = 0; k < H_; k += 4) {
            a0 = fmaf(sh_h[k + 0], whpT[(size_t)(k + 0) * A_ + tid], a0);
            a1 = fmaf(sh_h[k + 1], whpT[(size_t)(k + 1) * A_ + tid], a1);
            a2 = fmaf(sh_h[k + 2], whpT[(size_t)(k + 2) * A_ + tid], a2);
            a3 = fmaf(sh_h[k + 3], whpT[(size_t)(k + 3) * A_ + tid], a3);
        }
        sh_hp[tid] = (a0 + a1) + (a2 + a3) + b_hidp[tid];
    }
    __syncthreads();

    const int lane = tid & 63, wid = tid >> 6;
    for (int r = wid; r < R_; r += 8) {
        const ushort2* row = reinterpret_cast<const ushort2*>(fpb + ((size_t)b * R_ + r) * A_);
        float acc = 0.f;
        #pragma unroll
        for (int j = 0; j < 4; ++j) {
            const ushort2 u = row[lane + 64 * j];
            const int a = 2 * (lane + 64 * j);
            acc += fast_tanh(bf2f(u.x) + sh_hp[a]) * sh_ws[a];
            acc += fast_tanh(bf2f(u.y) + sh_hp[a + 1]) * sh_ws[a + 1];
        }
        for (int off = 32; off > 0; off >>= 1) acc += __shfl_down(acc, off);
        if (lane == 0) sh_sc[r] = acc + b_score[0];
    }
    __syncthreads();

    if (tid < 64) {
        float m = -1e30f;
        for (int r = tid; r < R_; r += 64) m = fmaxf(m, sh_sc[r]);
        for (int off = 32; off > 0; off >>= 1) m = fmaxf(m, __shfl_xor(m, off));
        float s = 0.f;
        for (int r = tid; r < R_; r += 64) s += __expf(sh_sc[r] - m);
        for (int off = 32; off > 0; off >>= 1) s += __shfl_xor(s, off);
        if (tid == 0) { red[0] = m; red[1] = 1.f / s; }
    }
    __syncthreads();
    const float m = red[0], is = red[1];
    if (tid < R_) {
        const float av = __expf(sh_sc[tid] - m) * is;
        alpha[b * R_ + tid] = av;
        alph_out[((size_t)b * L_ + t) * R_ + tid] = av;
    }
}

// context: block (fs 0..3, b): ctx[b, fs*512 + 2*tid + {0,1}] over all 196 r
__global__ __launch_bounds__(256) void ctx_kernel(
    const ush* __restrict__ fbh, const float* __restrict__ alpha,
    ush* __restrict__ ctx_hi, ush* __restrict__ ctx_lo)
{
    __shared__ float sa[R_];
    const int tid = threadIdx.x;
    const int fs = blockIdx.x;
    const int b = blockIdx.y;
    if (tid < R_) sa[tid] = alpha[b * R_ + tid];
    __syncthreads();

    const int f0 = fs * 512 + tid * 2;
    const ush* fp = fbh + (size_t)b * R_ * F_ + f0;
    float cx = 0.f, cy = 0.f;
    #pragma unroll 4
    for (int r = 0; r < R_; ++r) {
        const float a = sa[r];
        const ushort2 u = *(const ushort2*)(fp + (size_t)r * F_);
        cx = fmaf(a, bf2f(u.x), cx); cy = fmaf(a, bf2f(u.y), cy);
    }
    const size_t ci = (size_t)b * F_ + f0;
    const ush hx = f2bf(cx);
    ctx_hi[ci] = hx; ctx_lo[ci] = f2bf(cx - bf2f(hx));
    const ush hy = f2bf(cy);
    ctx_hi[ci + 1] = hy; ctx_lo[ci + 1] = f2bf(cy - bf2f(hy));
}

extern "C" void kernel_launch(void* const* d_in, const int* in_sizes, int n_in,
                              void* d_out, int out_size, void* d_ws, size_t ws_size,
                              hipStream_t stream)
{
    const float* feats    = (const float*)d_in[0];
    const int*   cap      = (const int*)  d_in[1];
    const float* emb      = (const float*)d_in[2];
    const float* W_init_h = (const float*)d_in[3];
    const float* b_init_h = (const float*)d_in[4];
    const float* W_init_c = (const float*)d_in[5];
    const float* b_init_c = (const float*)d_in[6];
    const float* W_ih     = (const float*)d_in[7];
    const float* b_ih     = (const float*)d_in[8];
    const float* W_hh     = (const float*)d_in[9];
    const float* b_hh     = (const float*)d_in[10];
    const float* W_featp  = (const float*)d_in[11];
    const float* b_featp  = (const float*)d_in[12];
    const float* W_hidp   = (const float*)d_in[13];
    const float* b_hidp   = (const float*)d_in[14];
    const float* W_score  = (const float*)d_in[15];
    const float* b_score  = (const float*)d_in[16];
    const float* W_out    = (const float*)d_in[17];
    const float* b_out    = (const float*)d_in[18];

    float* pred     = (float*)d_out;                          // (B,L,V)
    float* alph_out = pred + (size_t)B_ * L_ * V_;            // (B,L,R)

    char* p = (char*)d_ws;
    auto alloc = [&](size_t bytes) { char* q = p; p += (bytes + 255) & ~(size_t)255; return q; };

    ush*   fpb    = (ush*)  alloc((size_t)B_ * R_ * A_ * 2);
    ush*   eh     = (ush*)  alloc((size_t)B_ * L_ * E_ * 2);
    ush*   el     = (ush*)  alloc((size_t)B_ * L_ * E_ * 2);
    ush*   mh     = (ush*)  alloc((size_t)B_ * F_ * 2);
    ush*   ml     = (ush*)  alloc((size_t)B_ * F_ * 2);
    ush*   fbh    = (ush*)  alloc((size_t)B_ * R_ * F_ * 2);
    ush*   wfp_h  = (ush*)  alloc((size_t)A_ * F_ * 2);
    ush*   wiH    = (ush*)  alloc((size_t)1024 * F_ * 2);
    ush*   wiL    = (ush*)  alloc((size_t)1024 * F_ * 2);
    ush*   wxh    = (ush*)  alloc((size_t)2048 * E_ * 2);
    ush*   wxl    = (ush*)  alloc((size_t)2048 * E_ * 2);
    ush*   wg2h   = (ush*)  alloc((size_t)2048 * (F_ + H_) * 2);
    ush*   wg2l   = (ush*)  alloc((size_t)2048 * (F_ + H_) * 2);
    ush*   woh    = (ush*)  alloc((size_t)V_ * H_ * 2);
    ush*   wol    = (ush*)  alloc((size_t)V_ * H_ * 2);
    float* whpT   = (float*)alloc((size_t)H_ * A_ * 4);
    float* egates = (float*)alloc((size_t)B_ * L_ * 2048 * 4);
    float* h0f    = (float*)alloc((size_t)B_ * H_ * 4);
    float* c      = (float*)alloc((size_t)B_ * H_ * 4);
    ush*   h_hi   = (ush*)  alloc((size_t)B_ * H_ * 2);
    ush*   h_lo   = (ush*)  alloc((size_t)B_ * H_ * 2);
    ush*   hallh  = (ush*)  alloc((size_t)L_ * B_ * H_ * 2);
    ush*   halll  = (ush*)  alloc((size_t)L_ * B_ * H_ * 2);
    ush*   ctx_hi = (ush*)  alloc((size_t)B_ * F_ * 2);
    ush*   ctx_lo = (ush*)  alloc((size_t)B_ * F_ * 2);
    float* alpha  = (float*)alloc((size_t)B_ * R_ * 4);
    float* gparts = (float*)alloc((size_t)8 * B_ * 2048 * 4);
    float* initp  = (float*)alloc((size_t)8 * B_ * 1024 * 4);

    // ---- one-time prep ----
    prep_feats<<<dim3(4, B_), 256, 0, stream>>>(feats, fbh, mh, ml);
    gather_split<<<768, 256, 0, stream>>>(emb, cap, eh, el);
    split_kernel<<<2048, 256, 0, stream>>>(W_out, woh, wol, V_ * H_ / 4);
    split_kernel<<<512, 256, 0, stream>>>(W_init_h, wiH, wiL, H_ * F_ / 4);
    split_kernel<<<512, 256, 0, stream>>>(W_init_c, wiH + (size_t)512 * F_,
                                          wiL + (size_t)512 * F_, H_ * F_ / 4);
    split_kernel<<<512, 256, 0, stream>>>(W_featp, wfp_h, nullptr, A_ * F_ / 4);
    prep_wih<<<2048, 256, 0, stream>>>(W_ih, W_hh, wxh, wxl, wg2h, wg2l);
    transpose512<<<1024, 256, 0, stream>>>(W_hidp, whpT);

    // h0/c0 init: M=64, N=1024 (stacked), K=2048, split-K=8
    gemm_gates<<<dim3(16, 1, 8), 256, 0, stream>>>(
        mh, ml, F_, F_,
        mh, ml, F_,
        wiH, wiL, F_,
        initp, 1024, (long)B_ * 1024, F_ / 8);
    init_reduce<<<256, 256, 0, stream>>>(initp, b_init_h, b_init_c, h0f, c, h_hi, h_lo);

    // feat_proj (SPLIT=1, bf16 out, NF=2): M=12544, N=512 -> grid(196,4)=784
    gemm_big<1, 1, true, 2><<<dim3(196, 4), 256, 0, stream>>>(
        fbh, nullptr, F_, wfp_h, nullptr, F_, b_featp, fpb, A_, A_, F_);

    // emb gate part for ALL steps (SPLIT=3, NF=2): M=1536, N=2048 -> grid(24,16)=384
    gemm_big<3, 0, false, 2><<<dim3(24, 16), 256, 0, stream>>>(
        eh, el, E_, wxh, wxl, E_, nullptr, egates, 2048, 2048, E_);

    // ---- sequential decode: 3 kernels per step ----
    for (int t = 0; t < L_; ++t) {
        step_kernel<true><<<B_, 512, 0, stream>>>(
            gparts, egates, b_ih, b_hh, c, h0f, h_hi, h_lo, hallh, halll,
            whpT, b_hidp, fpb, W_score, b_score, alpha, alph_out, t);

        ctx_kernel<<<dim3(4, B_), 256, 0, stream>>>(fbh, alpha, ctx_hi, ctx_lo);

        gemm_gates<<<dim3(32, 1, 8), 256, 0, stream>>>(
            ctx_hi, ctx_lo, F_, F_,
            h_hi, h_lo, H_,
            wg2h, wg2l, F_ + H_,
            gparts, 4 * H_, (long)B_ * 4 * H_, (F_ + H_) / 8);
    }

    // final cell: h_L -> hall[L-1]
    step_kernel<false><<<B_, 512, 0, stream>>>(
        gparts, egates, b_ih, b_hh, c, h0f, h_hi, h_lo, hallh, halll,
        whpT, b_hidp, fpb, W_score, b_score, alpha, alph_out, L_);

    // predictions for ALL steps (SPLIT=3): M=1536 -> 12 tiles of 128, N=12000
    gemm_big128<3, 2, false><<<dim3(12, 47), 512, 0, stream>>>(
        hallh, halll, H_, woh, wol, H_, b_out, pred, 0, V_, H_);
}

// Round 10
// 1966.217 us; speedup vs baseline: 1.1743x; 1.0681x over previous
//
#include <hip/hip_runtime.h>

#define B_ 64
#define R_ 196
#define F_ 2048
#define E_ 512
#define H_ 512
#define A_ 512
#define V_ 12000
#define L_ 24

typedef __attribute__((ext_vector_type(8))) short bf16x8;
typedef __attribute__((ext_vector_type(4))) float f32x4;
typedef unsigned short ush;

__device__ __forceinline__ float fast_tanh(float x) {
    float t = __expf(2.f * x);
    return 1.f - 2.f / (t + 1.f);
}
__device__ __forceinline__ float fast_sig(float x) {
    return 1.f / (1.f + __expf(-x));
}
__device__ __forceinline__ ush f2bf(float x) {
    unsigned int u = __float_as_uint(x);
    return (ush)((u + 0x7fffu + ((u >> 16) & 1u)) >> 16);
}
__device__ __forceinline__ float bf2f(ush b) {
    return __uint_as_float(((unsigned int)b) << 16);
}

#define LROW 40   // LDS row stride (32 k-elems + 8 pad)

// ---------------------------------------------------------------------------
// gemm_big128: C = A @ W^T (+bias). Tile 128M x 256N, BK=32, 512 threads.
// Pred GEMM (564 blocks; WRITE-amp fixed by 128-tile). Bijective XCD swizzle.
// SPLIT=3: (hi,lo) bf16x2, 3 MFMAs. CMAP=2: pred layout, fp32 NT stores.
// ---------------------------------------------------------------------------
template<int SPLIT, int CMAP, bool NFAST>
__global__ __launch_bounds__(512) void gemm_big128(
    const ush* __restrict__ Ah, const ush* __restrict__ Al, int lda,
    const ush* __restrict__ Wh, const ush* __restrict__ Wl, int ldw,
    const float* __restrict__ bias, void* __restrict__ Cv,
    int ldc, int N, int K)
{
    constexpr int SMEM_BYTES = (SPLIT == 3) ? 61440 : 30720;
    __shared__ __align__(16) char smem[SMEM_BYTES];
    ush* sAh = (ush*)smem;
    ush* sBh = (ush*)(smem + 10240);
    ush* sAl = (ush*)(smem + 30720);
    ush* sBl = (ush*)(smem + 40960);

    const int tid = threadIdx.x;
    const int lane = tid & 63, w = tid >> 6;
    const int mw = w >> 2, nw = w & 3;

    const int nbx = gridDim.x, nby = gridDim.y;
    const int nwg = nbx * nby;
    const int orig = blockIdx.x + nbx * blockIdx.y;
    const int q = nwg >> 3, r = nwg & 7;
    const int xcd = orig & 7, idx = orig >> 3;
    const int lin = (xcd < r ? xcd * (q + 1) : r * (q + 1) + (xcd - r) * q) + idx;
    int bx, by;
    if constexpr (NFAST) { by = lin % nby; bx = lin / nby; }
    else                 { bx = lin % nbx; by = lin / nbx; }
    const int mtile = bx * 128;
    const int ntile = by * 256;

    const int fr = lane & 15, kg = (lane >> 4) * 8;
    const int arow = tid >> 2, aq = (tid & 3) * 8;

    f32x4 acc[4][4];
    #pragma unroll
    for (int mf = 0; mf < 4; ++mf)
        #pragma unroll
        for (int nf = 0; nf < 4; ++nf) acc[mf][nf] = {0.f, 0.f, 0.f, 0.f};

    const uint4 zv = make_uint4(0u, 0u, 0u, 0u);

    for (int kb = 0; kb < K; kb += 32) {
        uint4 a_h = *(const uint4*)(Ah + (size_t)(mtile + arow) * lda + kb + aq);
        uint4 a_l;
        uint4 b_h[2], b_l[2];
        #pragma unroll
        for (int p = 0; p < 2; ++p) {
            const int row = ntile + arow + 128 * p;
            b_h[p] = (row < N) ? *(const uint4*)(Wh + (size_t)row * ldw + kb + aq) : zv;
        }
        if constexpr (SPLIT == 3) {
            a_l = *(const uint4*)(Al + (size_t)(mtile + arow) * lda + kb + aq);
            #pragma unroll
            for (int p = 0; p < 2; ++p) {
                const int row = ntile + arow + 128 * p;
                b_l[p] = (row < N) ? *(const uint4*)(Wl + (size_t)row * ldw + kb + aq) : zv;
            }
        }

        __syncthreads();
        *(uint4*)(sAh + arow * LROW + aq) = a_h;
        #pragma unroll
        for (int p = 0; p < 2; ++p)
            *(uint4*)(sBh + (arow + 128 * p) * LROW + aq) = b_h[p];
        if constexpr (SPLIT == 3) {
            *(uint4*)(sAl + arow * LROW + aq) = a_l;
            #pragma unroll
            for (int p = 0; p < 2; ++p)
                *(uint4*)(sBl + (arow + 128 * p) * LROW + aq) = b_l[p];
        }
        __syncthreads();

        bf16x8 bh[4], bl[4];
        #pragma unroll
        for (int nf = 0; nf < 4; ++nf) {
            bh[nf] = *(const bf16x8*)(sBh + (nw * 64 + nf * 16 + fr) * LROW + kg);
            if constexpr (SPLIT == 3)
                bl[nf] = *(const bf16x8*)(sBl + (nw * 64 + nf * 16 + fr) * LROW + kg);
        }
        #pragma unroll
        for (int mf = 0; mf < 4; ++mf) {
            const bf16x8 ah = *(const bf16x8*)(sAh + (mw * 64 + mf * 16 + fr) * LROW + kg);
            if constexpr (SPLIT == 3) {
                const bf16x8 al = *(const bf16x8*)(sAl + (mw * 64 + mf * 16 + fr) * LROW + kg);
                #pragma unroll
                for (int nf = 0; nf < 4; ++nf) {
                    acc[mf][nf] = __builtin_amdgcn_mfma_f32_16x16x32_bf16(ah, bh[nf], acc[mf][nf], 0, 0, 0);
                    acc[mf][nf] = __builtin_amdgcn_mfma_f32_16x16x32_bf16(ah, bl[nf], acc[mf][nf], 0, 0, 0);
                    acc[mf][nf] = __builtin_amdgcn_mfma_f32_16x16x32_bf16(al, bh[nf], acc[mf][nf], 0, 0, 0);
                }
            } else {
                #pragma unroll
                for (int nf = 0; nf < 4; ++nf)
                    acc[mf][nf] = __builtin_amdgcn_mfma_f32_16x16x32_bf16(ah, bh[nf], acc[mf][nf], 0, 0, 0);
            }
        }
    }

    #pragma unroll
    for (int nf = 0; nf < 4; ++nf) {
        const int nn = ntile + nw * 64 + nf * 16 + fr;
        if (nn < N) {
            const float bv = bias ? bias[nn] : 0.f;
            #pragma unroll
            for (int mf = 0; mf < 4; ++mf) {
                #pragma unroll
                for (int rr = 0; rr < 4; ++rr) {
                    const int m = mtile + mw * 64 + mf * 16 + (lane >> 4) * 4 + rr;
                    const float v = acc[mf][nf][rr] + bv;
                    if constexpr (CMAP == 1)
                        ((ush*)Cv)[(size_t)m * ldc + nn] = f2bf(v);
                    else if constexpr (CMAP == 2) {
                        float* dst = (float*)Cv + (size_t)(m & 63) * (L_ * V_)
                                   + (size_t)(m >> 6) * V_ + nn;
                        __builtin_nontemporal_store(v, dst);
                    } else
                        ((float*)Cv)[(size_t)m * ldc + nn] = v;
                }
            }
        }
    }
}

// ---------------------------------------------------------------------------
// gemm_big: 64M x (64*NF)N tile, 256 threads. NF=1 -> 64x64 (max blocks).
// ---------------------------------------------------------------------------
template<int SPLIT, int CMAP, bool NFAST, int NF>
__global__ __launch_bounds__(256) void gemm_big(
    const ush* __restrict__ Ah, const ush* __restrict__ Al, int lda,
    const ush* __restrict__ Wh, const ush* __restrict__ Wl, int ldw,
    const float* __restrict__ bias, void* __restrict__ Cv,
    int ldc, int N, int K)
{
    constexpr int ABYTES = 64 * LROW * 2;
    constexpr int BBYTES = 64 * NF * LROW * 2;
    constexpr int SMEM_BYTES = (SPLIT == 3) ? 2 * (ABYTES + BBYTES) : (ABYTES + BBYTES);
    __shared__ __align__(16) char smem[SMEM_BYTES];
    ush* sAh = (ush*)smem;
    ush* sBh = (ush*)(smem + ABYTES);
    ush* sAl = (ush*)(smem + ABYTES + BBYTES);
    ush* sBl = (ush*)(smem + 2 * ABYTES + BBYTES);

    const int tid = threadIdx.x;
    const int lane = tid & 63, w = tid >> 6;

    const int nbx = gridDim.x, nby = gridDim.y;
    const int nwg = nbx * nby;
    int lin = blockIdx.x + nbx * blockIdx.y;
    if ((nwg & 7) == 0) {
        const int q = nwg >> 3;
        lin = (lin & 7) * q + (lin >> 3);
    }
    int bx, by;
    if constexpr (NFAST) { by = lin % nby; bx = lin / nby; }
    else                 { bx = lin % nbx; by = lin / nbx; }
    const int mtile = bx * 64;
    const int ntile = by * (64 * NF);

    const int fr = lane & 15, kg = (lane >> 4) * 8;
    const int arow = tid >> 2, aq = (tid & 3) * 8;

    f32x4 acc[4][NF];
    #pragma unroll
    for (int mf = 0; mf < 4; ++mf)
        #pragma unroll
        for (int nf = 0; nf < NF; ++nf) acc[mf][nf] = {0.f, 0.f, 0.f, 0.f};

    const uint4 zv = make_uint4(0u, 0u, 0u, 0u);

    for (int kb = 0; kb < K; kb += 32) {
        uint4 a_h = *(const uint4*)(Ah + (size_t)(mtile + arow) * lda + kb + aq);
        uint4 a_l;
        uint4 b_h[NF], b_l[NF];
        #pragma unroll
        for (int p = 0; p < NF; ++p) {
            const int row = ntile + arow + 64 * p;
            b_h[p] = (row < N) ? *(const uint4*)(Wh + (size_t)row * ldw + kb + aq) : zv;
        }
        if constexpr (SPLIT == 3) {
            a_l = *(const uint4*)(Al + (size_t)(mtile + arow) * lda + kb + aq);
            #pragma unroll
            for (int p = 0; p < NF; ++p) {
                const int row = ntile + arow + 64 * p;
                b_l[p] = (row < N) ? *(const uint4*)(Wl + (size_t)row * ldw + kb + aq) : zv;
            }
        }

        __syncthreads();
        *(uint4*)(sAh + arow * LROW + aq) = a_h;
        #pragma unroll
        for (int p = 0; p < NF; ++p)
            *(uint4*)(sBh + (arow + 64 * p) * LROW + aq) = b_h[p];
        if constexpr (SPLIT == 3) {
            *(uint4*)(sAl + arow * LROW + aq) = a_l;
            #pragma unroll
            for (int p = 0; p < NF; ++p)
                *(uint4*)(sBl + (arow + 64 * p) * LROW + aq) = b_l[p];
        }
        __syncthreads();

        bf16x8 bh[NF], bl[NF];
        #pragma unroll
        for (int nf = 0; nf < NF; ++nf) {
            bh[nf] = *(const bf16x8*)(sBh + (w * (16 * NF) + nf * 16 + fr) * LROW + kg);
            if constexpr (SPLIT == 3)
                bl[nf] = *(const bf16x8*)(sBl + (w * (16 * NF) + nf * 16 + fr) * LROW + kg);
        }
        #pragma unroll
        for (int mf = 0; mf < 4; ++mf) {
            const bf16x8 ah = *(const bf16x8*)(sAh + (mf * 16 + fr) * LROW + kg);
            if constexpr (SPLIT == 3) {
                const bf16x8 al = *(const bf16x8*)(sAl + (mf * 16 + fr) * LROW + kg);
                #pragma unroll
                for (int nf = 0; nf < NF; ++nf) {
                    acc[mf][nf] = __builtin_amdgcn_mfma_f32_16x16x32_bf16(ah, bh[nf], acc[mf][nf], 0, 0, 0);
                    acc[mf][nf] = __builtin_amdgcn_mfma_f32_16x16x32_bf16(ah, bl[nf], acc[mf][nf], 0, 0, 0);
                    acc[mf][nf] = __builtin_amdgcn_mfma_f32_16x16x32_bf16(al, bh[nf], acc[mf][nf], 0, 0, 0);
                }
            } else {
                #pragma unroll
                for (int nf = 0; nf < NF; ++nf)
                    acc[mf][nf] = __builtin_amdgcn_mfma_f32_16x16x32_bf16(ah, bh[nf], acc[mf][nf], 0, 0, 0);
            }
        }
    }

    #pragma unroll
    for (int nf = 0; nf < NF; ++nf) {
        const int nn = ntile + w * (16 * NF) + nf * 16 + fr;
        if (nn < N) {
            const float bv = bias ? bias[nn] : 0.f;
            #pragma unroll
            for (int mf = 0; mf < 4; ++mf) {
                #pragma unroll
                for (int rr = 0; rr < 4; ++rr) {
                    const int m = mtile + mf * 16 + (lane >> 4) * 4 + rr;
                    const float v = acc[mf][nf][rr] + bv;
                    if constexpr (CMAP == 1)
                        ((ush*)Cv)[(size_t)m * ldc + nn] = f2bf(v);
                    else
                        ((float*)Cv)[(size_t)m * ldc + nn] = v;
                }
            }
        }
    }
}

// ---------------------------------------------------------------------------
// gemm_gates: 64x64 tile, segmented A (2 segments), split-K via grid.z.
// ---------------------------------------------------------------------------
__global__ __launch_bounds__(256) void gemm_gates(
    const ush* __restrict__ Ah0, const ush* __restrict__ Al0, int lda0, int k0,
    const ush* __restrict__ Ah1, const ush* __restrict__ Al1, int lda1,
    const ush* __restrict__ Wh, const ush* __restrict__ Wl, int ldw,
    float* __restrict__ C, int ldc, long zstride, int kChunk)
{
    __shared__ ush sAh[64 * LROW];
    __shared__ ush sBh[64 * LROW];
    __shared__ ush sAl[64 * LROW];
    __shared__ ush sBl[64 * LROW];

    const int tid = threadIdx.x;
    const int ntile = blockIdx.x * 64;
    const int kStart = blockIdx.z * kChunk;
    const int lane = tid & 63, w = tid >> 6;
    const int lrow = tid >> 2;
    const int lcol = (tid & 3) * 8;
    const int nrow = ntile + lrow;

    f32x4 acc[4];
    #pragma unroll
    for (int f = 0; f < 4; ++f) acc[f] = {0.f, 0.f, 0.f, 0.f};

    const int fr = lane & 15;
    const int kg = (lane >> 4) * 8;

    for (int kb = kStart; kb < kStart + kChunk; kb += 32) {
        const ush *ph, *pl; int lda, loc;
        if (kb < k0) { ph = Ah0; pl = Al0; lda = lda0; loc = kb; }
        else         { ph = Ah1; pl = Al1; lda = lda1; loc = kb - k0; }

        uint4 a_h = *(const uint4*)(ph + (size_t)lrow * lda + loc + lcol);
        uint4 b_h = *(const uint4*)(Wh + (size_t)nrow * ldw + kb + lcol);
        uint4 a_l = *(const uint4*)(pl + (size_t)lrow * lda + loc + lcol);
        uint4 b_l = *(const uint4*)(Wl + (size_t)nrow * ldw + kb + lcol);

        __syncthreads();
        *(uint4*)(sAh + lrow * LROW + lcol) = a_h;
        *(uint4*)(sBh + lrow * LROW + lcol) = b_h;
        *(uint4*)(sAl + lrow * LROW + lcol) = a_l;
        *(uint4*)(sBl + lrow * LROW + lcol) = b_l;
        __syncthreads();

        const bf16x8 bh = *(const bf16x8*)(sBh + (16 * w + fr) * LROW + kg);
        const bf16x8 bl = *(const bf16x8*)(sBl + (16 * w + fr) * LROW + kg);

        #pragma unroll
        for (int f = 0; f < 4; ++f) {
            const bf16x8 ah = *(const bf16x8*)(sAh + (16 * f + fr) * LROW + kg);
            const bf16x8 al = *(const bf16x8*)(sAl + (16 * f + fr) * LROW + kg);
            acc[f] = __builtin_amdgcn_mfma_f32_16x16x32_bf16(ah, bh, acc[f], 0, 0, 0);
            acc[f] = __builtin_amdgcn_mfma_f32_16x16x32_bf16(ah, bl, acc[f], 0, 0, 0);
            acc[f] = __builtin_amdgcn_mfma_f32_16x16x32_bf16(al, bh, acc[f], 0, 0, 0);
        }
    }

    const int n = ntile + 16 * w + (lane & 15);
    float* Cz = C + (size_t)blockIdx.z * zstride;
    #pragma unroll
    for (int f = 0; f < 4; ++f)
        #pragma unroll
        for (int rr = 0; rr < 4; ++rr) {
            const int m = 16 * f + (lane >> 4) * 4 + rr;
            Cz[(size_t)m * ldc + n] = acc[f][rr];
        }
}

// fused feats pass: fbh (bf16) + per-(b,f) mean -> mh/ml. block (fs, b).
__global__ __launch_bounds__(256) void prep_feats(
    const float* __restrict__ feats, ush* __restrict__ fbh,
    ush* __restrict__ mh, ush* __restrict__ ml)
{
    const int fs = blockIdx.x;
    const int b  = blockIdx.y;
    const int f = fs * 512 + threadIdx.x * 2;
    const float2* fp = (const float2*)(feats + (size_t)b * R_ * F_ + f);
    ush* fo = fbh + (size_t)b * R_ * F_ + f;
    float sx = 0.f, sy = 0.f;
    for (int r = 0; r < R_; ++r) {
        const float2 v = fp[(size_t)r * (F_ / 2)];
        sx += v.x; sy += v.y;
        ushort2 u; u.x = f2bf(v.x); u.y = f2bf(v.y);
        *(ushort2*)(fo + (size_t)r * F_) = u;
    }
    const float s = 1.f / (float)R_;
    sx *= s; sy *= s;
    const size_t mi = (size_t)b * F_ + f;
    const ush hx = f2bf(sx); mh[mi] = hx;     ml[mi] = f2bf(sx - bf2f(hx));
    const ush hy = f2bf(sy); mh[mi + 1] = hy; ml[mi + 1] = f2bf(sy - bf2f(hy));
}

// gather embeddings -> bf16 hi/lo (B,L,E)
__global__ __launch_bounds__(256) void gather_split(
    const float* __restrict__ emb, const int* __restrict__ cap,
    ush* __restrict__ eh, ush* __restrict__ el)
{
    const int idx = blockIdx.x * 256 + threadIdx.x;
    const int bt = idx >> 7, j = idx & 127;
    const int tok = cap[bt];
    const float4 v = reinterpret_cast<const float4*>(emb)[(size_t)tok * (E_ / 4) + j];
    const float a[4] = {v.x, v.y, v.z, v.w};
    #pragma unroll
    for (int c = 0; c < 4; ++c) {
        const ush hi = f2bf(a[c]);
        eh[idx * 4 + c] = hi;
        el[idx * 4 + c] = f2bf(a[c] - bf2f(hi));
    }
}

// generic fp32 -> bf16 (hi, optional lo)
__global__ __launch_bounds__(256) void split_kernel(
    const float* __restrict__ in, ush* __restrict__ hi, ush* __restrict__ lo, int n4)
{
    for (int i = blockIdx.x * 256 + threadIdx.x; i < n4; i += gridDim.x * 256) {
        const float4 v = reinterpret_cast<const float4*>(in)[i];
        const float a[4] = {v.x, v.y, v.z, v.w};
        #pragma unroll
        for (int c = 0; c < 4; ++c) {
            const ush h = f2bf(a[c]);
            hi[i * 4 + c] = h;
            if (lo) lo[i * 4 + c] = f2bf(a[c] - bf2f(h));
        }
    }
}

// W_ih columns [0:E) -> wx (2048x512); [E:) ++ W_hh -> wg2 (2048x2560); hi/lo
__global__ __launch_bounds__(256) void prep_wih(
    const float* __restrict__ W_ih, const float* __restrict__ W_hh,
    ush* __restrict__ wxh, ush* __restrict__ wxl,
    ush* __restrict__ wg2h, ush* __restrict__ wg2l)
{
    const int nrow = blockIdx.x;
    for (int k = threadIdx.x; k < E_; k += 256) {
        const float v = W_ih[(size_t)nrow * (E_ + F_) + k];
        const ush h = f2bf(v);
        wxh[(size_t)nrow * E_ + k] = h;
        wxl[(size_t)nrow * E_ + k] = f2bf(v - bf2f(h));
    }
    for (int k = threadIdx.x; k < F_ + H_; k += 256) {
        const float v = (k < F_) ? W_ih[(size_t)nrow * (E_ + F_) + E_ + k]
                                 : W_hh[(size_t)nrow * H_ + (k - F_)];
        const ush h = f2bf(v);
        wg2h[(size_t)nrow * (F_ + H_) + k] = h;
        wg2l[(size_t)nrow * (F_ + H_) + k] = f2bf(v - bf2f(h));
    }
}

// transpose W_hidp (A x H) -> whpT (H x A), bf16
__global__ __launch_bounds__(256) void transpose512(
    const float* __restrict__ in, ush* __restrict__ out)
{
    const int idx = blockIdx.x * 256 + threadIdx.x;
    const int k = idx >> 9, a = idx & 511;
    out[idx] = f2bf(in[(size_t)a * 512 + k]);
}

// reduce init GEMM partials: n<512 -> h0 (+split), n>=512 -> c0 (buffer 0)
__global__ __launch_bounds__(256) void init_reduce(
    const float* __restrict__ initp, const float* __restrict__ b_init_h,
    const float* __restrict__ b_init_c, float* __restrict__ h0f,
    float* __restrict__ c0, ush* __restrict__ h_hi, ush* __restrict__ h_lo)
{
    const int idx = blockIdx.x * 256 + threadIdx.x;
    const int b = idx >> 10, n = idx & 1023;
    float s = 0.f;
    #pragma unroll
    for (int z = 0; z < 8; ++z)
        s += initp[(size_t)z * (B_ * 1024) + (size_t)b * 1024 + n];
    if (n < 512) {
        s += b_init_h[n];
        h0f[b * H_ + n] = s;
        const ush hi = f2bf(s);
        h_hi[b * H_ + n] = hi;
        h_lo[b * H_ + n] = f2bf(s - bf2f(hi));
    } else {
        s += b_init_c[n - 512];
        c0[b * H_ + (n - 512)] = s;
    }
}

// ---------------------------------------------------------------------------
// step2_kernel<ATT>: grid (4, B) when ATT (fs = f-quarter), (1, B) else.
// 512 threads. All fs-blocks redundantly compute cell -> h, hid_proj,
// scores, softmax (alpha in LDS); each block then computes its 512-f ctx
// quarter. Only fs==0 writes h/c/hall/alph_out. c is double-buffered:
// read c2[(t-1)&1], write c2[t&1] -- no cross-block race.
// ---------------------------------------------------------------------------
template<bool ATT>
__global__ __launch_bounds__(512) void step2_kernel(
    const float* __restrict__ gparts, const float* __restrict__ egates,
    const float* __restrict__ b_ih, const float* __restrict__ b_hh,
    float* __restrict__ c2, const float* __restrict__ h0f,
    ush* __restrict__ h_hi, ush* __restrict__ h_lo,
    ush* __restrict__ hall_hi, ush* __restrict__ hall_lo,
    const ush* __restrict__ whpT, const float* __restrict__ b_hidp,
    const ush* __restrict__ fpb, const float* __restrict__ W_score,
    const float* __restrict__ b_score, const ush* __restrict__ fbh,
    ush* __restrict__ ctx_hi, ush* __restrict__ ctx_lo,
    float* __restrict__ alph_out, int t)
{
    __shared__ float sh_h[H_];
    __shared__ float sh_hp[A_];
    __shared__ float sh_ws[A_];
    __shared__ float sh_sc[200];
    __shared__ float red[2];
    const int tid = threadIdx.x;
    const int fs = blockIdx.x;
    const int b = blockIdx.y;
    const int n = tid;

    float hh;
    if (t > 0) {
        const float* c_old = c2 + (size_t)((t - 1) & 1) * B_ * H_;
        float* c_new = c2 + (size_t)(t & 1) * B_ * H_;
        const float* eg = egates + ((size_t)b * L_ + (t - 1)) * 2048;
        float gi = b_ih[n] + b_hh[n] + eg[n];
        float gf = b_ih[n + 512] + b_hh[n + 512] + eg[n + 512];
        float gg = b_ih[n + 1024] + b_hh[n + 1024] + eg[n + 1024];
        float go = b_ih[n + 1536] + b_hh[n + 1536] + eg[n + 1536];
        #pragma unroll
        for (int z = 0; z < 8; ++z) {
            const float* gz = gparts + (size_t)z * B_ * 2048 + (size_t)b * 2048;
            gi += gz[n]; gf += gz[n + 512]; gg += gz[n + 1024]; go += gz[n + 1536];
        }
        const float cc = fast_sig(gf) * c_old[b * H_ + n] + fast_sig(gi) * fast_tanh(gg);
        hh = fast_sig(go) * fast_tanh(cc);
        if (fs == 0) {
            c_new[b * H_ + n] = cc;
            const ush hi = f2bf(hh);
            const ush lo = f2bf(hh - bf2f(hi));
            h_hi[b * H_ + n] = hi;
            h_lo[b * H_ + n] = lo;
            const size_t hidx = ((size_t)(t - 1) * B_ + b) * H_ + n;
            hall_hi[hidx] = hi;
            hall_lo[hidx] = lo;
        }
    } else {
        hh = h0f[b * H_ + n];
    }
    if constexpr (!ATT) return;

    sh_h[n] = hh;
    sh_ws[n] = W_score[n];
    __syncthreads();

    // hid_proj (coalesced, bf16 whpT)
    {
        float a0 = 0.f, a1 = 0.f, a2 = 0.f, a3 = 0.f;
        #pragma unroll 4
        for (int k = 0; k < H_; k += 4) {
            a0 = fmaf(sh_h[k + 0], bf2f(whpT[(size_t)(k + 0) * A_ + tid]), a0);
            a1 = fmaf(sh_h[k + 1], bf2f(whpT[(size_t)(k + 1) * A_ + tid]), a1);
            a2 = fmaf(sh_h[k + 2], bf2f(whpT[(size_t)(k + 2) * A_ + tid]), a2);
            a3 = fmaf(sh_h[k + 3], bf2f(whpT[(size_t)(k + 3) * A_ + tid]), a3);
        }
        sh_hp[tid] = (a0 + a1) + (a2 + a3) + b_hidp[tid];
    }
    __syncthreads();

    const int lane = tid & 63, wid = tid >> 6;
    for (int r = wid; r < R_; r += 8) {
        const ushort2* row = reinterpret_cast<const ushort2*>(fpb + ((size_t)b * R_ + r) * A_);
        float acc = 0.f;
        #pragma unroll
        for (int j = 0; j < 4; ++j) {
            const ushort2 u = row[lane + 64 * j];
            const int a = 2 * (lane + 64 * j);
            acc += fast_tanh(bf2f(u.x) + sh_hp[a]) * sh_ws[a];
            acc += fast_tanh(bf2f(u.y) + sh_hp[a + 1]) * sh_ws[a + 1];
        }
        for (int off = 32; off > 0; off >>= 1) acc += __shfl_down(acc, off);
        if (lane == 0) sh_sc[r] = acc + b_score[0];
    }
    __syncthreads();

    if (tid < 64) {
        float m = -1e30f;
        for (int r = tid; r < R_; r += 64) m = fmaxf(m, sh_sc[r]);
        for (int off = 32; off > 0; off >>= 1) m = fmaxf(m, __shfl_xor(m, off));
        float s = 0.f;
        for (int r = tid; r < R_; r += 64) s += __expf(sh_sc[r] - m);
        for (int off = 32; off > 0; off >>= 1) s += __shfl_xor(s, off);
        if (tid == 0) { red[0] = m; red[1] = 1.f / s; }
    }
    __syncthreads();
    const float m = red[0], is = red[1];
    if (tid < R_) {
        const float av = __expf(sh_sc[tid] - m) * is;
        sh_sc[tid] = av;
        if (fs == 0) alph_out[((size_t)b * L_ + t) * R_ + tid] = av;
    }
    __syncthreads();

    // ---- ctx quarter: f = fs*512 + tid, sum over 196 regions (bf16 fbh) ----
    {
        const int f0 = fs * 512 + tid;
        const ush* fp2 = fbh + (size_t)b * R_ * F_ + f0;
        float cx = 0.f;
        #pragma unroll 4
        for (int r = 0; r < R_; ++r)
            cx = fmaf(sh_sc[r], bf2f(fp2[(size_t)r * F_]), cx);
        const size_t ci = (size_t)b * F_ + f0;
        const ush hx = f2bf(cx);
        ctx_hi[ci] = hx;
        ctx_lo[ci] = f2bf(cx - bf2f(hx));
    }
}

extern "C" void kernel_launch(void* const* d_in, const int* in_sizes, int n_in,
                              void* d_out, int out_size, void* d_ws, size_t ws_size,
                              hipStream_t stream)
{
    const float* feats    = (const float*)d_in[0];
    const int*   cap      = (const int*)  d_in[1];
    const float* emb      = (const float*)d_in[2];
    const float* W_init_h = (const float*)d_in[3];
    const float* b_init_h = (const float*)d_in[4];
    const float* W_init_c = (const float*)d_in[5];
    const float* b_init_c = (const float*)d_in[6];
    const float* W_ih     = (const float*)d_in[7];
    const float* b_ih     = (const float*)d_in[8];
    const float* W_hh     = (const float*)d_in[9];
    const float* b_hh     = (const float*)d_in[10];
    const float* W_featp  = (const float*)d_in[11];
    const float* b_featp  = (const float*)d_in[12];
    const float* W_hidp   = (const float*)d_in[13];
    const float* b_hidp   = (const float*)d_in[14];
    const float* W_score  = (const float*)d_in[15];
    const float* b_score  = (const float*)d_in[16];
    const float* W_out    = (const float*)d_in[17];
    const float* b_out    = (const float*)d_in[18];

    float* pred     = (float*)d_out;                          // (B,L,V)
    float* alph_out = pred + (size_t)B_ * L_ * V_;            // (B,L,R)

    char* p = (char*)d_ws;
    auto alloc = [&](size_t bytes) { char* q = p; p += (bytes + 255) & ~(size_t)255; return q; };

    ush*   fpb    = (ush*)  alloc((size_t)B_ * R_ * A_ * 2);
    ush*   eh     = (ush*)  alloc((size_t)B_ * L_ * E_ * 2);
    ush*   el     = (ush*)  alloc((size_t)B_ * L_ * E_ * 2);
    ush*   mh     = (ush*)  alloc((size_t)B_ * F_ * 2);
    ush*   ml     = (ush*)  alloc((size_t)B_ * F_ * 2);
    ush*   fbh    = (ush*)  alloc((size_t)B_ * R_ * F_ * 2);
    ush*   wfp_h  = (ush*)  alloc((size_t)A_ * F_ * 2);
    ush*   wiH    = (ush*)  alloc((size_t)1024 * F_ * 2);
    ush*   wiL    = (ush*)  alloc((size_t)1024 * F_ * 2);
    ush*   wxh    = (ush*)  alloc((size_t)2048 * E_ * 2);
    ush*   wxl    = (ush*)  alloc((size_t)2048 * E_ * 2);
    ush*   wg2h   = (ush*)  alloc((size_t)2048 * (F_ + H_) * 2);
    ush*   wg2l   = (ush*)  alloc((size_t)2048 * (F_ + H_) * 2);
    ush*   woh    = (ush*)  alloc((size_t)V_ * H_ * 2);
    ush*   wol    = (ush*)  alloc((size_t)V_ * H_ * 2);
    ush*   whpT   = (ush*)  alloc((size_t)H_ * A_ * 2);
    float* egates = (float*)alloc((size_t)B_ * L_ * 2048 * 4);
    float* h0f    = (float*)alloc((size_t)B_ * H_ * 4);
    float* c2     = (float*)alloc((size_t)2 * B_ * H_ * 4);   // double-buffered c
    ush*   h_hi   = (ush*)  alloc((size_t)B_ * H_ * 2);
    ush*   h_lo   = (ush*)  alloc((size_t)B_ * H_ * 2);
    ush*   hallh  = (ush*)  alloc((size_t)L_ * B_ * H_ * 2);
    ush*   halll  = (ush*)  alloc((size_t)L_ * B_ * H_ * 2);
    ush*   ctx_hi = (ush*)  alloc((size_t)B_ * F_ * 2);
    ush*   ctx_lo = (ush*)  alloc((size_t)B_ * F_ * 2);
    float* gparts = (float*)alloc((size_t)8 * B_ * 2048 * 4);
    float* initp  = (float*)alloc((size_t)8 * B_ * 1024 * 4);

    // ---- one-time prep ----
    prep_feats<<<dim3(4, B_), 256, 0, stream>>>(feats, fbh, mh, ml);
    gather_split<<<768, 256, 0, stream>>>(emb, cap, eh, el);
    split_kernel<<<2048, 256, 0, stream>>>(W_out, woh, wol, V_ * H_ / 4);
    split_kernel<<<512, 256, 0, stream>>>(W_init_h, wiH, wiL, H_ * F_ / 4);
    split_kernel<<<512, 256, 0, stream>>>(W_init_c, wiH + (size_t)512 * F_,
                                          wiL + (size_t)512 * F_, H_ * F_ / 4);
    split_kernel<<<512, 256, 0, stream>>>(W_featp, wfp_h, nullptr, A_ * F_ / 4);
    prep_wih<<<2048, 256, 0, stream>>>(W_ih, W_hh, wxh, wxl, wg2h, wg2l);
    transpose512<<<1024, 256, 0, stream>>>(W_hidp, whpT);

    // h0/c0 init: M=64, N=1024 (stacked), K=2048, split-K=8
    gemm_gates<<<dim3(16, 1, 8), 256, 0, stream>>>(
        mh, ml, F_, F_,
        mh, ml, F_,
        wiH, wiL, F_,
        initp, 1024, (long)B_ * 1024, F_ / 8);
    init_reduce<<<256, 256, 0, stream>>>(initp, b_init_h, b_init_c, h0f, c2, h_hi, h_lo);

    // feat_proj (SPLIT=1, bf16 out, NF=1): 64x64 tiles -> grid(196,8)=1568
    gemm_big<1, 1, true, 1><<<dim3(196, 8), 256, 0, stream>>>(
        fbh, nullptr, F_, wfp_h, nullptr, F_, b_featp, fpb, A_, A_, F_);

    // emb gate part for ALL steps (SPLIT=3, NF=2): grid(24,16)=384
    gemm_big<3, 0, false, 2><<<dim3(24, 16), 256, 0, stream>>>(
        eh, el, E_, wxh, wxl, E_, nullptr, egates, 2048, 2048, E_);

    // ---- sequential decode: 2 kernels per step ----
    for (int t = 0; t < L_; ++t) {
        step2_kernel<true><<<dim3(4, B_), 512, 0, stream>>>(
            gparts, egates, b_ih, b_hh, c2, h0f, h_hi, h_lo, hallh, halll,
            whpT, b_hidp, fpb, W_score, b_score, fbh, ctx_hi, ctx_lo,
            alph_out, t);

        gemm_gates<<<dim3(32, 1, 8), 256, 0, stream>>>(
            ctx_hi, ctx_lo, F_, F_,
            h_hi, h_lo, H_,
            wg2h, wg2l, F_ + H_,
            gparts, 4 * H_, (long)B_ * 4 * H_, (F_ + H_) / 8);
    }

    // final cell: h_L -> hall[L-1]
    step2_kernel<false><<<dim3(1, B_), 512, 0, stream>>>(
        gparts, egates, b_ih, b_hh, c2, h0f, h_hi, h_lo, hallh, halll,
        whpT, b_hidp, fpb, W_score, b_score, fbh, ctx_hi, ctx_lo,
        alph_out, L_);

    // predictions for ALL steps (SPLIT=3): M=1536 -> 12 tiles of 128, N=12000
    gemm_big128<3, 2, false><<<dim3(12, 47), 512, 0, stream>>>(
        hallh, halll, H_, woh, wol, H_, b_out, pred, 0, V_, H_);
}